// Round 7
// baseline (299.553 us; speedup 1.0000x reference)
//
#include <hip/hip_runtime.h>
#include <stdint.h>
#include <stddef.h>

// Problem constants
#define HB 8
#define HN 1024
#define HC 768
#define HH 12
#define HD 64
#define ROWS (HB*HN)      // 8192
#define BH (HB*HH)        // 96

using s16x4  = __attribute__((ext_vector_type(4))) short;
using bf16x8 = __attribute__((ext_vector_type(8))) short;
using f32x4  = __attribute__((ext_vector_type(4))) float;

__device__ __forceinline__ short f2bf(float f) {
  union { float f; uint32_t u; } c; c.f = f;
  uint32_t u = c.u;
  uint32_t r = (u + 0x7fffu + ((u >> 16) & 1u)) >> 16;   // RNE
  return (short)r;
}
__device__ __forceinline__ float bf2f(short s) {
  union { uint32_t u; float f; } c; c.u = ((uint32_t)(uint16_t)s) << 16;
  return c.f;
}
// pack two f32 -> {bf16(a) | bf16(b)<<16} with RNE, via v_perm_b32
__device__ __forceinline__ uint32_t pack_bf16_rne(float a, float b) {
  union { float f; uint32_t u; } ca, cb; ca.f = a; cb.f = b;
  uint32_t ra = ca.u + 0x7fffu + ((ca.u >> 16) & 1u);
  uint32_t rb = cb.u + 0x7fffu + ((cb.u >> 16) & 1u);
  return __builtin_amdgcn_perm(rb, ra, 0x07060302);  // {rb[31:16], ra[31:16]}
}
__device__ __forceinline__ float fast_exp2(float x) {
#if __has_builtin(__builtin_amdgcn_exp2f)
  return __builtin_amdgcn_exp2f(x);
#else
  return exp2f(x);
#endif
}
__device__ __forceinline__ f32x4 mfma16(bf16x8 a, bf16x8 b, f32x4 c) {
  return __builtin_amdgcn_mfma_f32_16x16x32_bf16(a, b, c, 0, 0, 0);
}
// async global->LDS, 16B per lane. LDS dest MUST be wave-uniform base + lane*16.
__device__ __forceinline__ void gll16(const void* g, void* l) {
  __builtin_amdgcn_global_load_lds((const __attribute__((address_space(1))) void*)g,
                                   (__attribute__((address_space(3))) void*)l,
                                   16, 0, 0);
}

// ---------------- f32 -> bf16 convert, weights only (R15: x-part fused) -----
__global__ void cvt2_kernel(const float* __restrict__ wq, short* __restrict__ wqb, int n0,
                            const float* __restrict__ wp, short* __restrict__ wpb, int n1) {
  int i = blockIdx.x * 256 + threadIdx.x;        // index in float4 units
  const float* in; short* out;
  if (i < n0)            { in = wq; out = wqb; }
  else if (i < n0 + n1)  { i -= n0; in = wp; out = wpb; }
  else return;
  float4 v = ((const float4*)in)[i];
  s16x4 o;
  o.x = f2bf(v.x); o.y = f2bf(v.y); o.z = f2bf(v.z); o.w = f2bf(v.w);
  ((s16x4*)out)[i] = o;
}

// ---------------- GEMM 1: qkv = x*Wqkv^T ------------------------------------
// R11 pipeline: BM=256 BN=128 BK=32, 512 thr (8 waves, 4Mx2N), 3 LDS slots.
// R12: v-epilogue writes Vtb directly (key-permuted transpose via LDS reuse).
// R15: A-tiles reg-staged from f32 x (load float4 -> RNE pack -> ds_write),
// eliminating cvt3's x pass (37.8 MB traffic). Issue FIFO per iteration:
// [A-f32(kt+3) x4, B-gll16(kt+2)] (A-before-B pinned by sched_barrier);
// top-of-iter wait = vmcnt(1) (drains prev iter's A x4 + B, keeps newest B
// in flight) + lgkmcnt(0) (ds_write visibility across the barrier).
template<int VM, bool LOADA, bool STGB, bool WRA, int SLOT>
__device__ __forceinline__ void qkv_ktile(
    int kt, short* sA, short* sB,
    const float* Ax, const short* Bg,
    int wr, int wc, int quad, int lc,
    int axoff0, int axoff1, int boff0,    // per-thread source offsets (elements)
    int cA0, int cA1, int cB0,            // per-thread LDS chunk ids
    float4 (&av)[4],
    f32x4 (&acc)[4][4])
{
  if constexpr (VM == 1) asm volatile("s_waitcnt vmcnt(1) lgkmcnt(0)" ::: "memory");
  else                   asm volatile("s_waitcnt vmcnt(0) lgkmcnt(0)" ::: "memory");
  __builtin_amdgcn_s_barrier();
  constexpr int DST = (SLOT + 2) % 3;
  if constexpr (WRA) {
    // write A(kt+2) into the slot freed at end of kt-1 (regs loaded at kt-1)
    short* dA = sA + DST*8192;
    uint4 w0, w1;
    w0.x = pack_bf16_rne(av[0].x, av[0].y); w0.y = pack_bf16_rne(av[0].z, av[0].w);
    w0.z = pack_bf16_rne(av[1].x, av[1].y); w0.w = pack_bf16_rne(av[1].z, av[1].w);
    w1.x = pack_bf16_rne(av[2].x, av[2].y); w1.y = pack_bf16_rne(av[2].z, av[2].w);
    w1.z = pack_bf16_rne(av[3].x, av[3].y); w1.w = pack_bf16_rne(av[3].z, av[3].w);
    *(uint4*)(dA + cA0*8) = w0;
    *(uint4*)(dA + cA1*8) = w1;
  }
  if constexpr (LOADA) {                  // A-f32 loads for tile kt+3 (FIFO first)
    const int kc = (kt + 3) * 32;
    av[0] = *(const float4*)(Ax + axoff0 + kc);
    av[1] = *(const float4*)(Ax + axoff0 + kc + 4);
    av[2] = *(const float4*)(Ax + axoff1 + kc);
    av[3] = *(const float4*)(Ax + axoff1 + kc + 4);
  }
  __builtin_amdgcn_sched_barrier(0);      // pin: A loads issue before B gll16
  if constexpr (STGB) {                   // B stage for tile kt+2 (FIFO last)
    short* dB = sB + DST*4096;
    gll16(Bg + (size_t)(boff0 + (kt + 2) * 32), (void*)(dB + cB0*8));
  }
  const short* sa = sA + SLOT*8192;
  const short* sb = sB + SLOT*4096;
  bf16x8 af[4], bfr[4];
#pragma unroll
  for (int mt = 0; mt < 4; ++mt) {
    const int rA = wr*64 + mt*16 + lc;
    af[mt] = *(const bf16x8*)(sa + rA*32 + (quad ^ ((rA >> 1) & 3))*8);
  }
#pragma unroll
  for (int nt = 0; nt < 4; ++nt) {
    const int rB = wc*64 + nt*16 + lc;
    bfr[nt] = *(const bf16x8*)(sb + rB*32 + (quad ^ ((rB >> 1) & 3))*8);
  }
  __builtin_amdgcn_s_setprio(1);
#pragma unroll
  for (int mt = 0; mt < 4; ++mt)
#pragma unroll
    for (int nt = 0; nt < 4; ++nt)
      acc[mt][nt] = mfma16(af[mt], bfr[nt], acc[mt][nt]);
  __builtin_amdgcn_s_setprio(0);
}

__global__ __launch_bounds__(512, 4) void gemm_qkv(const float* __restrict__ X,
                                                   const short* __restrict__ Bw,
                                                   short* __restrict__ Qb,
                                                   short* __restrict__ Kb,
                                                   short* __restrict__ Vtb) {
  __shared__ short SMEM[3*256*32 + 3*128*32];   // 72 KiB, reused by v-epilogue
  short* As = SMEM;                 // 3 x [256][32]
  short* Bs = SMEM + 3*256*32;      // 3 x [128][32]
  // XCD-bijective swizzle: 576 wgs = 8 XCDs x 72 (4 m-panels x 18 n) each.
  const int wg = blockIdx.x;
  const int swz = (wg & 7)*72 + (wg >> 3);
  const int by = swz / 18, bx = swz % 18;
  const int m0 = by*256, n0 = bx*128;
  const int tid = threadIdx.x;
  const int lane = tid & 63, w = tid >> 6, quad = lane >> 4, lc = lane & 15;
  const int wr = w >> 1, wc = w & 1;           // 4 x 2 wave grid
  // staging: A tile 256x32 = 1024 16B-chunks (2/thread); B 128x32 = 512 (1/thread)
  // chunk c: r = c>>2, cb = c&3; source col pre-swizzled cb ^ ((r>>1)&3)
  const int cA0 = tid,        rA0 = cA0 >> 2, sbA0 = ((cA0 & 3) ^ ((rA0 >> 1) & 3))*8;
  const int cA1 = 512 + tid,  rA1 = cA1 >> 2, sbA1 = ((cA1 & 3) ^ ((rA1 >> 1) & 3))*8;
  const int cB0 = tid,        rB0 = cB0 >> 2, sbB0 = ((cB0 & 3) ^ ((rB0 >> 1) & 3))*8;
  const int axoff0 = rA0*HC + sbA0;            // f32-element offsets into X panel
  const int axoff1 = rA1*HC + sbA1;
  const int boff0  = rB0*HC + sbB0;
  const float* Ax = X  + (size_t)m0*HC;
  const short* Bg = Bw + (size_t)n0*HC;
  f32x4 acc[4][4] = {};
  float4 av[4];

  // ---- prologue ----
  // A tiles 0,1: f32 load -> pack -> ds_write into slots 0,1
  {
    float4 p0[4], p1[4];
    p0[0] = *(const float4*)(Ax + axoff0);      p0[1] = *(const float4*)(Ax + axoff0 + 4);
    p0[2] = *(const float4*)(Ax + axoff1);      p0[3] = *(const float4*)(Ax + axoff1 + 4);
    p1[0] = *(const float4*)(Ax + axoff0 + 32); p1[1] = *(const float4*)(Ax + axoff0 + 36);
    p1[2] = *(const float4*)(Ax + axoff1 + 32); p1[3] = *(const float4*)(Ax + axoff1 + 36);
    asm volatile("s_waitcnt vmcnt(0)" ::: "memory");
#pragma unroll
    for (int t = 0; t < 2; ++t) {
      float4* p = t ? p1 : p0;
      short* dA = As + t*8192;
      uint4 w0, w1;
      w0.x = pack_bf16_rne(p[0].x, p[0].y); w0.y = pack_bf16_rne(p[0].z, p[0].w);
      w0.z = pack_bf16_rne(p[1].x, p[1].y); w0.w = pack_bf16_rne(p[1].z, p[1].w);
      w1.x = pack_bf16_rne(p[2].x, p[2].y); w1.y = pack_bf16_rne(p[2].z, p[2].w);
      w1.z = pack_bf16_rne(p[3].x, p[3].y); w1.w = pack_bf16_rne(p[3].z, p[3].w);
      *(uint4*)(dA + cA0*8) = w0;
      *(uint4*)(dA + cA1*8) = w1;
    }
  }
  __builtin_amdgcn_sched_barrier(0);
  // batch(-1) FIFO: [A(2) x4, B(0), B(1)]  -> top of kt=0 waits vmcnt(1)
  av[0] = *(const float4*)(Ax + axoff0 + 64);
  av[1] = *(const float4*)(Ax + axoff0 + 68);
  av[2] = *(const float4*)(Ax + axoff1 + 64);
  av[3] = *(const float4*)(Ax + axoff1 + 68);
  __builtin_amdgcn_sched_barrier(0);
  gll16(Bg + (size_t)(boff0 +  0), (void*)(Bs + 0*4096 + cB0*8));
  gll16(Bg + (size_t)(boff0 + 32), (void*)(Bs + 1*4096 + cB0*8));

  // main loop: K-tiles 0..20 (7 x 3 for compile-time slots), tail 21..23
#pragma unroll 1
  for (int kt = 0; kt < 21; kt += 3) {
    qkv_ktile<1,true,true,true,0>(kt,   As, Bs, Ax, Bg, wr, wc, quad, lc,
                                  axoff0, axoff1, boff0, cA0, cA1, cB0, av, acc);
    qkv_ktile<1,true,true,true,1>(kt+1, As, Bs, Ax, Bg, wr, wc, quad, lc,
                                  axoff0, axoff1, boff0, cA0, cA1, cB0, av, acc);
    qkv_ktile<1,true,true,true,2>(kt+2, As, Bs, Ax, Bg, wr, wc, quad, lc,
                                  axoff0, axoff1, boff0, cA0, cA1, cB0, av, acc);
  }
  qkv_ktile<1,false,true ,true ,0>(21, As, Bs, Ax, Bg, wr, wc, quad, lc,
                                   axoff0, axoff1, boff0, cA0, cA1, cB0, av, acc);
  qkv_ktile<1,false,false,false,1>(22, As, Bs, Ax, Bg, wr, wc, quad, lc,
                                   axoff0, axoff1, boff0, cA0, cA1, cB0, av, acc);
  qkv_ktile<0,false,false,false,2>(23, As, Bs, Ax, Bg, wr, wc, quad, lc,
                                   axoff0, axoff1, boff0, cA0, cA1, cB0, av, acc);

  // epilogue (C/D: col=nt*16+lc, row=quad*4+r); per-wave 64-col group = 1 head
  const int cg = n0 + wc*64;
  const int t = cg / HC;                // 0=q, 1=k, 2=v (block-uniform: n0 % 128 == 0)
  const int h = (cg % HC) / HD;
  if (t < 2) {
    short* outp = (t == 0) ? Qb : Kb;
    const float sc = (t == 0) ? 0.125f : 1.0f;   // SCALE = 64^-0.5 for q
#pragma unroll
    for (int i = 0; i < 4; ++i)
#pragma unroll
      for (int r = 0; r < 4; ++r) {
        float s1 = (acc[i][0][r] + acc[i][1][r]) + (acc[i][2][r] + acc[i][3][r]);
        float s2 = acc[i][0][r]*acc[i][0][r];
        s2 = __builtin_fmaf(acc[i][1][r], acc[i][1][r], s2);
        s2 = __builtin_fmaf(acc[i][2][r], acc[i][2][r], s2);
        s2 = __builtin_fmaf(acc[i][3][r], acc[i][3][r], s2);
#pragma unroll
        for (int off = 1; off < 16; off <<= 1) {
          s1 += __shfl_xor(s1, off);
          s2 += __shfl_xor(s2, off);
        }
        const float mean = s1 * (1.0f/64.0f);
        const float var  = s2 * (1.0f/64.0f) - mean*mean;
        const float inv  = rsqrtf(var + 1e-5f) * sc;
        const int row = m0 + wr*64 + i*16 + quad*4 + r;
        const int b = row >> 10, n_in = row & 1023;
        short* rowp = outp + ((size_t)(b*HH + h)*HN + n_in)*HD;
#pragma unroll
        for (int nt = 0; nt < 4; ++nt)
          rowp[nt*16 + lc] = f2bf((acc[i][nt][r] - mean) * inv);
      }
  } else {
    // fused V-transpose: acc -> LDS (key-permuted, stride 268) -> Vtb.
    // Storage col c holds key k: c(k) = ((k&15)<<2)|(k>>4); inverse of
    // attn's perm(c) = (c&3)*16 + (c>>2)  [perm(c(k)) == k].
    short* vs = SMEM;                 // [2][64][268] = 34304 shorts <= 36864
    __syncthreads();                  // main-loop LDS fully consumed by all waves
    const int hd = wc;                // wave's head slot (0/1)
#pragma unroll
    for (int i = 0; i < 4; ++i)
#pragma unroll
      for (int nt = 0; nt < 4; ++nt)
#pragma unroll
        for (int r = 0; r < 4; ++r) {
          const int dd = nt*16 + lc;
          const int k  = i*16 + quad*4 + r;            // row within 64-group
          const int c  = ((k & 15) << 2) | (k >> 4);   // permuted col
          vs[(hd*64 + dd)*268 + wr*64 + c] = f2bf(acc[i][nt][r]);
        }
    __syncthreads();
    const int b = m0 >> 10, m0g = m0 & 1023;
#pragma unroll
    for (int it = 0; it < 8; ++it) {
      const int idx = it*512 + tid;        // [0,4096)
      const int h2 = idx >> 11;            // head slot 0/1
      const int rem = idx & 2047;
      const int dd = rem >> 5, c8 = rem & 31;
      const int habs = ((n0 + h2*64) - 1536) >> 6;     // absolute head
      const short* src = vs + (h2*64 + dd)*268 + c8*8; // 8B-aligned
      s16x4 lo = *(const s16x4*)(src);
      s16x4 hi = *(const s16x4*)(src + 4);
      bf16x8 vvv;
      vvv[0]=lo[0]; vvv[1]=lo[1]; vvv[2]=lo[2]; vvv[3]=lo[3];
      vvv[4]=hi[0]; vvv[5]=hi[1]; vvv[6]=hi[2]; vvv[7]=hi[3];
      *(bf16x8*)(Vtb + ((size_t)((b*HH + habs)*HD + dd))*HN + m0g + c8*8) = vvv;
    }
  }
}

// ---------------- GEMM 2: out = AO * Wproj^T (f32 out) ----------------------
// R14: R11 counted-vmcnt pipeline. BM=128 BN=128 BK=32, 256 thr (4 waves),
// 3 LDS slots = 48 KiB -> 3 blocks/CU; grid 384 co-resident, no tail.
template<int VM, bool STG, int SLOT>
__device__ __forceinline__ void bt_ktile(
    int kt, short* sA, short* sB,
    const short* Ag, const short* Bg,
    int wr, int wc, int quad, int lc,
    int aoff0, int aoff1, int boff0, int boff1,
    int cA0, int cA1, int cB0, int cB1,
    f32x4 (&acc)[4][4])
{
  if constexpr (VM == 4) asm volatile("s_waitcnt vmcnt(4)" ::: "memory");
  else                   asm volatile("s_waitcnt vmcnt(0)" ::: "memory");
  __builtin_amdgcn_s_barrier();
  if constexpr (STG) {
    constexpr int DST = (SLOT + 2) % 3;
    const int kcol = (kt + 2) * 32;
    short* dA = sA + DST*4096;
    short* dB = sB + DST*4096;
    gll16(Ag + (size_t)(aoff0 + kcol), (void*)(dA + cA0*8));
    gll16(Ag + (size_t)(aoff1 + kcol), (void*)(dA + cA1*8));
    gll16(Bg + (size_t)(boff0 + kcol), (void*)(dB + cB0*8));
    gll16(Bg + (size_t)(boff1 + kcol), (void*)(dB + cB1*8));
  }
  const short* sa = sA + SLOT*4096;
  const short* sb = sB + SLOT*4096;
  bf16x8 af[4], bfr[4];
#pragma unroll
  for (int mt = 0; mt < 4; ++mt) {
    const int rA = wr*64 + mt*16 + lc;
    af[mt] = *(const bf16x8*)(sa + rA*32 + (quad ^ ((rA >> 1) & 3))*8);
  }
#pragma unroll
  for (int nt = 0; nt < 4; ++nt) {
    const int rB = wc*64 + nt*16 + lc;
    bfr[nt] = *(const bf16x8*)(sb + rB*32 + (quad ^ ((rB >> 1) & 3))*8);
  }
  __builtin_amdgcn_s_setprio(1);
#pragma unroll
  for (int mt = 0; mt < 4; ++mt)
#pragma unroll
    for (int nt = 0; nt < 4; ++nt)
      acc[mt][nt] = mfma16(af[mt], bfr[nt], acc[mt][nt]);
  __builtin_amdgcn_s_setprio(0);
}

__global__ __launch_bounds__(256, 3) void gemm_bt_f32(const short* __restrict__ A,
                                                      const short* __restrict__ Bw,
                                                      float* __restrict__ C) {
  __shared__ short As[3*128*32];   // 24 KiB
  __shared__ short Bs[3*128*32];   // 24 KiB
  // XCD swizzle: 384 wgs = 8 XCDs x 48 (8 m-panels x 6 n) each.
  const int wg = blockIdx.x;
  const int swz = (wg & 7)*48 + (wg >> 3);
  const int by = swz / 6, bx = swz % 6;
  const int m0 = by*128, n0 = bx*128;
  const int tid = threadIdx.x;
  const int lane = tid & 63, w = tid >> 6, quad = lane >> 4, lc = lane & 15;
  const int wr = w >> 1, wc = w & 1;           // 2 x 2 wave grid
  const int cA0 = tid,        rA0 = cA0 >> 2, sbA0 = ((cA0 & 3) ^ ((rA0 >> 1) & 3))*8;
  const int cA1 = 256 + tid,  rA1 = cA1 >> 2, sbA1 = ((cA1 & 3) ^ ((rA1 >> 1) & 3))*8;
  const int aoff0 = rA0*HC + sbA0;
  const int aoff1 = rA1*HC + sbA1;
  const int cB0 = cA0, cB1 = cA1;
  const int boff0 = aoff0, boff1 = aoff1;      // same mapping, B base differs
  const short* Ag = A  + (size_t)m0*HC;
  const short* Bg = Bw + (size_t)n0*HC;
  f32x4 acc[4][4] = {};

#pragma unroll
  for (int pk = 0; pk < 2; ++pk) {
    gll16(Ag + (size_t)(aoff0 + pk*32), (void*)(As + pk*4096 + cA0*8));
    gll16(Ag + (size_t)(aoff1 + pk*32), (void*)(As + pk*4096 + cA1*8));
    gll16(Bg + (size_t)(boff0 + pk*32), (void*)(Bs + pk*4096 + cB0*8));
    gll16(Bg + (size_t)(boff1 + pk*32), (void*)(Bs + pk*4096 + cB1*8));
  }

#pragma unroll 1
  for (int kt = 0; kt < 21; kt += 3) {
    bt_ktile<4,true,0>(kt,   As, Bs, Ag, Bg, wr, wc, quad, lc,
                       aoff0, aoff1, boff0, boff1, cA0, cA1, cB0, cB1, acc);
    bt_ktile<4,true,1>(kt+1, As, Bs, Ag, Bg, wr, wc, quad, lc,
                       aoff0, aoff1, boff0, boff1, cA0, cA1, cB0, cB1, acc);
    bt_ktile<4,true,2>(kt+2, As, Bs, Ag, Bg, wr, wc, quad, lc,
                       aoff0, aoff1, boff0, boff1, cA0, cA1, cB0, cB1, acc);
  }
  bt_ktile<4,true ,0>(21, As, Bs, Ag, Bg, wr, wc, quad, lc,
                      aoff0, aoff1, boff0, boff1, cA0, cA1, cB0, cB1, acc);  // stages T23
  bt_ktile<4,false,1>(22, As, Bs, Ag, Bg, wr, wc, quad, lc,
                      aoff0, aoff1, boff0, boff1, cA0, cA1, cB0, cB1, acc);
  bt_ktile<0,false,2>(23, As, Bs, Ag, Bg, wr, wc, quad, lc,
                      aoff0, aoff1, boff0, boff1, cA0, cA1, cB0, cB1, acc);

#pragma unroll
  for (int mt = 0; mt < 4; ++mt)
#pragma unroll
    for (int nt = 0; nt < 4; ++nt)
#pragma unroll
      for (int r = 0; r < 4; ++r) {
        const int row = m0 + wr*64 + mt*16 + quad*4 + r;
        const int col = n0 + wc*64 + nt*16 + lc;
        C[(size_t)row*HC + col] = acc[mt][nt][r];
      }
}

// ---------------- flash attention: 128 q-rows/block, 64-key chunks ----------
// R9 structure; R13: XCD-grouped block swizzle (all 8 q-tiles of each bh on
// one XCD -> per-XCD K/V working set 12*256KB = 3MB fits the 4MB L2).
__global__ __launch_bounds__(256, 3) void attn_kernel(const short* __restrict__ Qb,
                                                      const short* __restrict__ Kb,
                                                      const short* __restrict__ Vtb,
                                                      short* __restrict__ AOb) {
  const int raw = blockIdx.x;
  const int blk = (raw & 7)*96 + (raw >> 3);   // bijective on [0,768)
  const int qt = blk & 7, bh = blk >> 3;
  const int b = bh / HH, h = bh % HH;
  const int tid = threadIdx.x, w = tid >> 6, lane = tid & 63;
  const int quad = lane >> 4, lc = lane & 15;

  __shared__ short Ks [64][72];      // K chunk: row=key(natural), padded
  __shared__ short Vts[64][72];      // V chunk: row=d, cols=64 keys permuted
  __shared__ short Ps [4][32][72];   // per-wave P stash (32 q-rows), permuted keys

  // Q A-fragments: A[m=lane&15][k=quad*8+j]; wave rows qt*128 + w*32 + mt*16
  bf16x8 aq[2][2];
#pragma unroll
  for (int mt = 0; mt < 2; ++mt) {
    const int mrow = qt*128 + w*32 + mt*16 + lc;
    aq[mt][0] = *(const bf16x8*)(Qb + ((size_t)bh*HN + mrow)*HD + quad*8);
    aq[mt][1] = *(const bf16x8*)(Qb + ((size_t)bh*HN + mrow)*HD + 32 + quad*8);
  }

  const short* kbh = Kb  + (size_t)bh*HN*HD;
  const short* vbh = Vtb + (size_t)bh*HD*HN;

  f32x4 oacc[2][4] = {};
  float l_i[2][4] = {};

  // staging regs: c = i*256+tid in [0,512); row=c>>3 in [0,64), cb=c&7
  bf16x8 gk[2], gv[2];
#pragma unroll
  for (int i = 0; i < 2; ++i) {
    const int c = i*256 + tid;
    gk[i] = *(const bf16x8*)(kbh + (size_t)(c >> 3)*HD + (c & 7)*8);
    gv[i] = *(const bf16x8*)(vbh + (size_t)(c >> 3)*HN + (c & 7)*8);
  }
#pragma unroll
  for (int i = 0; i < 2; ++i) {
    const int c = i*256 + tid;
    *(bf16x8*)(&Ks [c >> 3][(c & 7)*8]) = gk[i];
    *(bf16x8*)(&Vts[c >> 3][(c & 7)*8]) = gv[i];
  }
  __syncthreads();

  const float LOG2E = 1.44269504f;
  const float MB2   = 8.0f * 1.44269504f;   // fixed max * log2(e)

  for (int ck = 0; ck < 16; ++ck) {
    // prefetch chunk ck+1 into registers (overlaps with compute below)
    if (ck < 15) {
      const int nn0 = (ck + 1)*64;
#pragma unroll
      for (int i = 0; i < 2; ++i) {
        const int c = i*256 + tid;
        gk[i] = *(const bf16x8*)(kbh + (size_t)(nn0 + (c >> 3))*HD + (c & 7)*8);
        gv[i] = *(const bf16x8*)(vbh + (size_t)(c >> 3)*HN + nn0 + (c & 7)*8);
      }
    }

    // S = Q K^T : 16 MFMAs (2 m-tiles x 2 kk x 4 nt)
    f32x4 sacc[2][4] = {};
#pragma unroll
    for (int kk = 0; kk < 2; ++kk)
#pragma unroll
      for (int nt = 0; nt < 4; ++nt) {
        bf16x8 bk = *(const bf16x8*)(&Ks[nt*16 + lc][kk*32 + quad*8]);
#pragma unroll
        for (int mt = 0; mt < 2; ++mt)
          sacc[mt][nt] = mfma16(aq[mt][kk], bk, sacc[mt][nt]);
      }

    // fixed-max softmax + P stash (C->A relayout, ds_write_b64 per row)
#pragma unroll
    for (int mt = 0; mt < 2; ++mt)
#pragma unroll
      for (int r = 0; r < 4; ++r) {
        float ps[4];
#pragma unroll
        for (int nt = 0; nt < 4; ++nt) {
          ps[nt] = fast_exp2(__builtin_fmaf(sacc[mt][nt][r], LOG2E, -MB2));
          sacc[mt][nt][r] = ps[nt];
        }
        l_i[mt][r] += (ps[0] + ps[1]) + (ps[2] + ps[3]);
        uint2 pk;
        pk.x = pack_bf16_rne(ps[0], ps[1]);
        pk.y = pack_bf16_rne(ps[2], ps[3]);
        *(uint2*)(&Ps[w][mt*16 + quad*4 + r][lc*4]) = pk;
      }

    // O += P V : 16 MFMAs (A from Ps, B from Vts; both in permuted key space)
#pragma unroll
    for (int kk = 0; kk < 2; ++kk) {
      bf16x8 ap[2];
#pragma unroll
      for (int mt = 0; mt < 2; ++mt)
        ap[mt] = *(const bf16x8*)(&Ps[w][mt*16 + lc][kk*32 + quad*8]);
#pragma unroll
      for (int nt2 = 0; nt2 < 4; ++nt2) {
        bf16x8 bv = *(const bf16x8*)(&Vts[nt2*16 + lc][kk*32 + quad*8]);
#pragma unroll
        for (int mt = 0; mt < 2; ++mt)
          oacc[mt][nt2] = mfma16(ap[mt], bv, oacc[mt][nt2]);
      }
    }

    if (ck < 15) {
      __syncthreads();   // all waves done reading Ks/Vts
#pragma unroll
      for (int i = 0; i < 2; ++i) {
        const int c = i*256 + tid;
        *(bf16x8*)(&Ks [c >> 3][(c & 7)*8]) = gk[i];
        *(bf16x8*)(&Vts[c >> 3][(c & 7)*8]) = gv[i];
      }
      __syncthreads();
    }
  }

  // epilogue: reduce l across the 16 lanes of each quad, then scale & store
#pragma unroll
  for (int mt = 0; mt < 2; ++mt)
#pragma unroll
    for (int r = 0; r < 4; ++r) {
      float l = l_i[mt][r];
#pragma unroll
      for (int off = 1; off < 16; off <<= 1) l += __shfl_xor(l, off);
      const float rl = 1.0f / l;
      const int row = qt*128 + w*32 + mt*16 + quad*4 + r;
#pragma unroll
      for (int nt2 = 0; nt2 < 4; ++nt2) {
        const int d = nt2*16 + lc;
        AOb[((size_t)(b*HN + row))*HC + h*HD + d] = f2bf(oacc[mt][nt2][r] * rl);
      }
    }
}

// ---------------- launch ----------------
extern "C" void kernel_launch(void* const* d_in, const int* in_sizes, int n_in,
                              void* d_out, int out_size, void* d_ws, size_t ws_size,
                              hipStream_t stream) {
  const float* x     = (const float*)d_in[0];
  const float* wqkv  = (const float*)d_in[1];
  const float* wproj = (const float*)d_in[2];
  float* out = (float*)d_out;

  char* ws = (char*)d_ws;
  size_t off = 0;
  auto alloc = [&](size_t bytes) -> void* {
    void* p = ws + off; off += (bytes + 255) & ~(size_t)255; return p;
  };
  short* wqkvb  = (short*)alloc((size_t)3*HC*HC*2);        //  3.5 MB
  short* wprojb = (short*)alloc((size_t)HC*HC*2);          //  1.2 MB
  short* Qb     = (short*)alloc((size_t)BH*HN*HD*2);       // 12.6 MB
  short* Kb     = (short*)alloc((size_t)BH*HN*HD*2);       // 12.6 MB
  short* Vtb    = (short*)alloc((size_t)BH*HD*HN*2);       // 12.6 MB
  short* AOb    = (short*)alloc((size_t)ROWS*HC*2);        // 12.6 MB  (~55 MB total)

  { const int n0 = 3*HC*HC/4, n1 = HC*HC/4;
    const int tot = n0 + n1;
    cvt2_kernel<<<(tot + 255)/256, 256, 0, stream>>>(wqkv, wqkvb, n0,
                                                     wproj, wprojb, n1); }

  // 576 = 32 m-blocks x 18 n-blocks, XCD-swizzled inside the kernel
  gemm_qkv<<<dim3(576), 512, 0, stream>>>(x, wqkvb, Qb, Kb, Vtb);
  attn_kernel<<<BH*8, 256, 0, stream>>>(Qb, Kb, Vtb, AOb);
  // 384 = 64 m-blocks x 6 n-blocks, XCD-swizzled inside the kernel
  gemm_bt_f32<<<dim3(384), 256, 0, stream>>>(AOb, wprojb, out);
}

// Round 8
// 186.222 us; speedup vs baseline: 1.6086x; 1.6086x over previous
//
#include <hip/hip_runtime.h>
#include <stdint.h>
#include <stddef.h>

// Problem constants
#define HB 8
#define HN 1024
#define HC 768
#define HH 12
#define HD 64
#define ROWS (HB*HN)      // 8192
#define BH (HB*HH)        // 96

using s16x4  = __attribute__((ext_vector_type(4))) short;
using bf16x8 = __attribute__((ext_vector_type(8))) short;
using f32x4  = __attribute__((ext_vector_type(4))) float;

__device__ __forceinline__ short f2bf(float f) {
  union { float f; uint32_t u; } c; c.f = f;
  uint32_t u = c.u;
  uint32_t r = (u + 0x7fffu + ((u >> 16) & 1u)) >> 16;   // RNE
  return (short)r;
}
__device__ __forceinline__ float bf2f(short s) {
  union { uint32_t u; float f; } c; c.u = ((uint32_t)(uint16_t)s) << 16;
  return c.f;
}
// pack two f32 -> {bf16(a) | bf16(b)<<16} with RNE, via v_perm_b32
__device__ __forceinline__ uint32_t pack_bf16_rne(float a, float b) {
  union { float f; uint32_t u; } ca, cb; ca.f = a; cb.f = b;
  uint32_t ra = ca.u + 0x7fffu + ((ca.u >> 16) & 1u);
  uint32_t rb = cb.u + 0x7fffu + ((cb.u >> 16) & 1u);
  return __builtin_amdgcn_perm(rb, ra, 0x07060302);  // {rb[31:16], ra[31:16]}
}
__device__ __forceinline__ float fast_exp2(float x) {
#if __has_builtin(__builtin_amdgcn_exp2f)
  return __builtin_amdgcn_exp2f(x);
#else
  return exp2f(x);
#endif
}
__device__ __forceinline__ f32x4 mfma16(bf16x8 a, bf16x8 b, f32x4 c) {
  return __builtin_amdgcn_mfma_f32_16x16x32_bf16(a, b, c, 0, 0, 0);
}
// async global->LDS, 16B per lane. LDS dest MUST be wave-uniform base + lane*16.
__device__ __forceinline__ void gll16(const void* g, void* l) {
  __builtin_amdgcn_global_load_lds((const __attribute__((address_space(1))) void*)g,
                                   (__attribute__((address_space(3))) void*)l,
                                   16, 0, 0);
}

// ---------------- fused f32 -> bf16 convert for all 3 inputs ----------------
// (R16: restored — R15's in-GEMM x conversion spilled to scratch: WRITE_SIZE
// 37->264MB, MfmaUtil 23->6%. Keep the standalone pass.)
__global__ void cvt3_kernel(const float* __restrict__ x,  short* __restrict__ xb,  int n0,
                            const float* __restrict__ wq, short* __restrict__ wqb, int n1,
                            const float* __restrict__ wp, short* __restrict__ wpb, int n2) {
  int i = blockIdx.x * 256 + threadIdx.x;        // index in float4 units
  const float* in; short* out;
  if (i < n0)            { in = x;  out = xb;  }
  else if (i < n0 + n1)  { i -= n0; in = wq; out = wqb; }
  else if (i < n0 + n1 + n2) { i -= n0 + n1; in = wp; out = wpb; }
  else return;
  float4 v = ((const float4*)in)[i];
  s16x4 o;
  o.x = f2bf(v.x); o.y = f2bf(v.y); o.z = f2bf(v.z); o.w = f2bf(v.w);
  ((s16x4*)out)[i] = o;
}

// ---------------- GEMM 1: qkv = x*Wqkv^T ------------------------------------
// R11 pipeline (proven): BM=256 BN=128 BK=32, 512 thr (8 waves, 4Mx2N),
// 3 LDS slots, 2-deep staging, one barrier + one vmcnt(3) per K-tile.
// R12: v-epilogue writes Vtb DIRECTLY (key-permuted transpose via LDS reuse).
template<int VM, bool STG, int SLOT>
__device__ __forceinline__ void qkv_ktile(
    int kt, short* sA, short* sB,
    const short* Ag, const short* Bg,
    int wr, int wc, int quad, int lc,
    int aoff0, int aoff1, int boff0,      // per-thread source offsets (row*HC+swz-col)
    int cA0, int cA1, int cB0,            // per-thread LDS chunk ids
    f32x4 (&acc)[4][4])
{
  // T(kt) landed for THIS wave; barrier makes it true for ALL waves.
  if constexpr (VM == 3) asm volatile("s_waitcnt vmcnt(3)" ::: "memory");
  else                   asm volatile("s_waitcnt vmcnt(0)" ::: "memory");
  __builtin_amdgcn_s_barrier();
  // After the barrier every wave finished iteration kt-1 (incl. its ds_reads
  // of slot (kt-1)%3) -> safe to stage kt+2 into that slot.
  if constexpr (STG) {
    constexpr int DST = (SLOT + 2) % 3;
    const int kcol = (kt + 2) * 32;
    short* dA = sA + DST*8192;
    short* dB = sB + DST*4096;
    gll16(Ag + (size_t)(aoff0 + kcol), (void*)(dA + cA0*8));
    gll16(Ag + (size_t)(aoff1 + kcol), (void*)(dA + cA1*8));
    gll16(Bg + (size_t)(boff0 + kcol), (void*)(dB + cB0*8));
  }
  const short* sa = sA + SLOT*8192;
  const short* sb = sB + SLOT*4096;
  bf16x8 af[4], bfr[4];
#pragma unroll
  for (int mt = 0; mt < 4; ++mt) {
    const int rA = wr*64 + mt*16 + lc;
    af[mt] = *(const bf16x8*)(sa + rA*32 + (quad ^ ((rA >> 1) & 3))*8);
  }
#pragma unroll
  for (int nt = 0; nt < 4; ++nt) {
    const int rB = wc*64 + nt*16 + lc;
    bfr[nt] = *(const bf16x8*)(sb + rB*32 + (quad ^ ((rB >> 1) & 3))*8);
  }
  __builtin_amdgcn_s_setprio(1);
#pragma unroll
  for (int mt = 0; mt < 4; ++mt)
#pragma unroll
    for (int nt = 0; nt < 4; ++nt)
      acc[mt][nt] = mfma16(af[mt], bfr[nt], acc[mt][nt]);
  __builtin_amdgcn_s_setprio(0);
}

__global__ __launch_bounds__(512, 4) void gemm_qkv(const short* __restrict__ A,
                                                   const short* __restrict__ Bw,
                                                   short* __restrict__ Qb,
                                                   short* __restrict__ Kb,
                                                   short* __restrict__ Vtb) {
  __shared__ short SMEM[3*256*32 + 3*128*32];   // 72 KiB, reused by v-epilogue
  short* As = SMEM;                 // 3 x [256][32]
  short* Bs = SMEM + 3*256*32;      // 3 x [128][32]
  // XCD-bijective swizzle: 576 wgs = 8 XCDs x 72 (4 m-panels x 18 n) each.
  const int wg = blockIdx.x;
  const int swz = (wg & 7)*72 + (wg >> 3);
  const int by = swz / 18, bx = swz % 18;
  const int m0 = by*256, n0 = bx*128;
  const int tid = threadIdx.x;
  const int lane = tid & 63, w = tid >> 6, quad = lane >> 4, lc = lane & 15;
  const int wr = w >> 1, wc = w & 1;           // 4 x 2 wave grid
  // staging: A tile 256x32 = 1024 16B-chunks (2/thread); B 128x32 = 512 (1/thread)
  // chunk c: r = c>>2, cb = c&3; source col pre-swizzled cb ^ ((r>>1)&3)
  const int cA0 = tid,        rA0 = cA0 >> 2, sbA0 = ((cA0 & 3) ^ ((rA0 >> 1) & 3))*8;
  const int cA1 = 512 + tid,  rA1 = cA1 >> 2, sbA1 = ((cA1 & 3) ^ ((rA1 >> 1) & 3))*8;
  const int cB0 = tid,        rB0 = cB0 >> 2, sbB0 = ((cB0 & 3) ^ ((rB0 >> 1) & 3))*8;
  const int aoff0 = rA0*HC + sbA0;
  const int aoff1 = rA1*HC + sbA1;
  const int boff0 = rB0*HC + sbB0;
  const short* Ag = A  + (size_t)m0*HC;
  const short* Bg = Bw + (size_t)n0*HC;
  f32x4 acc[4][4] = {};

  // prologue: stage K-tiles 0 and 1 (FIFO order: T0's 3 loads, then T1's 3)
#pragma unroll
  for (int pk = 0; pk < 2; ++pk) {
    gll16(Ag + (size_t)(aoff0 + pk*32), (void*)(As + pk*8192 + cA0*8));
    gll16(Ag + (size_t)(aoff1 + pk*32), (void*)(As + pk*8192 + cA1*8));
    gll16(Bg + (size_t)(boff0 + pk*32), (void*)(Bs + pk*4096 + cB0*8));
  }

  // main loop: 24 K-tiles, unrolled by 3 so the slot index is compile-time
#pragma unroll 1
  for (int kt = 0; kt < 21; kt += 3) {
    qkv_ktile<3,true,0>(kt,   As, Bs, Ag, Bg, wr, wc, quad, lc,
                        aoff0, aoff1, boff0, cA0, cA1, cB0, acc);
    qkv_ktile<3,true,1>(kt+1, As, Bs, Ag, Bg, wr, wc, quad, lc,
                        aoff0, aoff1, boff0, cA0, cA1, cB0, acc);
    qkv_ktile<3,true,2>(kt+2, As, Bs, Ag, Bg, wr, wc, quad, lc,
                        aoff0, aoff1, boff0, cA0, cA1, cB0, acc);
  }
  qkv_ktile<3,true ,0>(21, As, Bs, Ag, Bg, wr, wc, quad, lc,
                       aoff0, aoff1, boff0, cA0, cA1, cB0, acc);   // stages T23
  qkv_ktile<3,false,1>(22, As, Bs, Ag, Bg, wr, wc, quad, lc,
                       aoff0, aoff1, boff0, cA0, cA1, cB0, acc);
  qkv_ktile<0,false,2>(23, As, Bs, Ag, Bg, wr, wc, quad, lc,
                       aoff0, aoff1, boff0, cA0, cA1, cB0, acc);

  // epilogue (C/D: col=nt*16+lc, row=quad*4+r); per-wave 64-col group = 1 head
  const int cg = n0 + wc*64;
  const int t = cg / HC;                // 0=q, 1=k, 2=v (block-uniform: n0 % 128 == 0)
  const int h = (cg % HC) / HD;
  if (t < 2) {
    short* outp = (t == 0) ? Qb : Kb;
    const float sc = (t == 0) ? 0.125f : 1.0f;   // SCALE = 64^-0.5 for q
#pragma unroll
    for (int i = 0; i < 4; ++i)
#pragma unroll
      for (int r = 0; r < 4; ++r) {
        float s1 = (acc[i][0][r] + acc[i][1][r]) + (acc[i][2][r] + acc[i][3][r]);
        float s2 = acc[i][0][r]*acc[i][0][r];
        s2 = __builtin_fmaf(acc[i][1][r], acc[i][1][r], s2);
        s2 = __builtin_fmaf(acc[i][2][r], acc[i][2][r], s2);
        s2 = __builtin_fmaf(acc[i][3][r], acc[i][3][r], s2);
#pragma unroll
        for (int off = 1; off < 16; off <<= 1) {
          s1 += __shfl_xor(s1, off);
          s2 += __shfl_xor(s2, off);
        }
        const float mean = s1 * (1.0f/64.0f);
        const float var  = s2 * (1.0f/64.0f) - mean*mean;
        const float inv  = rsqrtf(var + 1e-5f) * sc;
        const int row = m0 + wr*64 + i*16 + quad*4 + r;
        const int b = row >> 10, n_in = row & 1023;
        short* rowp = outp + ((size_t)(b*HH + h)*HN + n_in)*HD;
#pragma unroll
        for (int nt = 0; nt < 4; ++nt)
          rowp[nt*16 + lc] = f2bf((acc[i][nt][r] - mean) * inv);
      }
  } else {
    // fused V-transpose: acc -> LDS (key-permuted, stride 268) -> Vtb.
    // Storage col c holds key k: c(k) = ((k&15)<<2)|(k>>4); inverse of
    // attn's perm(c) = (c&3)*16 + (c>>2)  [perm(c(k)) == k].
    short* vs = SMEM;                 // [2][64][268] = 34304 shorts <= 36864
    __syncthreads();                  // main-loop LDS fully consumed by all waves
    const int hd = wc;                // wave's head slot (0/1)
#pragma unroll
    for (int i = 0; i < 4; ++i)
#pragma unroll
      for (int nt = 0; nt < 4; ++nt)
#pragma unroll
        for (int r = 0; r < 4; ++r) {
          const int dd = nt*16 + lc;
          const int k  = i*16 + quad*4 + r;            // row within 64-group
          const int c  = ((k & 15) << 2) | (k >> 4);   // permuted col
          vs[(hd*64 + dd)*268 + wr*64 + c] = f2bf(acc[i][nt][r]);
        }
    __syncthreads();
    const int b = m0 >> 10, m0g = m0 & 1023;
#pragma unroll
    for (int it = 0; it < 8; ++it) {
      const int idx = it*512 + tid;        // [0,4096)
      const int h2 = idx >> 11;            // head slot 0/1
      const int rem = idx & 2047;
      const int dd = rem >> 5, c8 = rem & 31;
      const int habs = ((n0 + h2*64) - 1536) >> 6;     // absolute head
      const short* src = vs + (h2*64 + dd)*268 + c8*8; // 8B-aligned
      s16x4 lo = *(const s16x4*)(src);
      s16x4 hi = *(const s16x4*)(src + 4);
      bf16x8 vvv;
      vvv[0]=lo[0]; vvv[1]=lo[1]; vvv[2]=lo[2]; vvv[3]=lo[3];
      vvv[4]=hi[0]; vvv[5]=hi[1]; vvv[6]=hi[2]; vvv[7]=hi[3];
      *(bf16x8*)(Vtb + ((size_t)((b*HH + habs)*HD + dd))*HN + m0g + c8*8) = vvv;
    }
  }
}

// ---------------- GEMM 2: out = AO * Wproj^T (f32 out) ----------------------
// R14: R11 counted-vmcnt pipeline. BM=128 BN=128 BK=32, 256 thr (4 waves),
// 3 LDS slots = 48 KiB -> 3 blocks/CU; grid 384 co-resident, no tail.
template<int VM, bool STG, int SLOT>
__device__ __forceinline__ void bt_ktile(
    int kt, short* sA, short* sB,
    const short* Ag, const short* Bg,
    int wr, int wc, int quad, int lc,
    int aoff0, int aoff1, int boff0, int boff1,
    int cA0, int cA1, int cB0, int cB1,
    f32x4 (&acc)[4][4])
{
  if constexpr (VM == 4) asm volatile("s_waitcnt vmcnt(4)" ::: "memory");
  else                   asm volatile("s_waitcnt vmcnt(0)" ::: "memory");
  __builtin_amdgcn_s_barrier();
  if constexpr (STG) {
    constexpr int DST = (SLOT + 2) % 3;
    const int kcol = (kt + 2) * 32;
    short* dA = sA + DST*4096;
    short* dB = sB + DST*4096;
    gll16(Ag + (size_t)(aoff0 + kcol), (void*)(dA + cA0*8));
    gll16(Ag + (size_t)(aoff1 + kcol), (void*)(dA + cA1*8));
    gll16(Bg + (size_t)(boff0 + kcol), (void*)(dB + cB0*8));
    gll16(Bg + (size_t)(boff1 + kcol), (void*)(dB + cB1*8));
  }
  const short* sa = sA + SLOT*4096;
  const short* sb = sB + SLOT*4096;
  bf16x8 af[4], bfr[4];
#pragma unroll
  for (int mt = 0; mt < 4; ++mt) {
    const int rA = wr*64 + mt*16 + lc;
    af[mt] = *(const bf16x8*)(sa + rA*32 + (quad ^ ((rA >> 1) & 3))*8);
  }
#pragma unroll
  for (int nt = 0; nt < 4; ++nt) {
    const int rB = wc*64 + nt*16 + lc;
    bfr[nt] = *(const bf16x8*)(sb + rB*32 + (quad ^ ((rB >> 1) & 3))*8);
  }
  __builtin_amdgcn_s_setprio(1);
#pragma unroll
  for (int mt = 0; mt < 4; ++mt)
#pragma unroll
    for (int nt = 0; nt < 4; ++nt)
      acc[mt][nt] = mfma16(af[mt], bfr[nt], acc[mt][nt]);
  __builtin_amdgcn_s_setprio(0);
}

__global__ __launch_bounds__(256, 3) void gemm_bt_f32(const short* __restrict__ A,
                                                      const short* __restrict__ Bw,
                                                      float* __restrict__ C) {
  __shared__ short As[3*128*32];   // 24 KiB
  __shared__ short Bs[3*128*32];   // 24 KiB
  // XCD swizzle: 384 wgs = 8 XCDs x 48 (8 m-panels x 6 n) each.
  const int wg = blockIdx.x;
  const int swz = (wg & 7)*48 + (wg >> 3);
  const int by = swz / 6, bx = swz % 6;
  const int m0 = by*128, n0 = bx*128;
  const int tid = threadIdx.x;
  const int lane = tid & 63, w = tid >> 6, quad = lane >> 4, lc = lane & 15;
  const int wr = w >> 1, wc = w & 1;           // 2 x 2 wave grid
  const int cA0 = tid,        rA0 = cA0 >> 2, sbA0 = ((cA0 & 3) ^ ((rA0 >> 1) & 3))*8;
  const int cA1 = 256 + tid,  rA1 = cA1 >> 2, sbA1 = ((cA1 & 3) ^ ((rA1 >> 1) & 3))*8;
  const int aoff0 = rA0*HC + sbA0;
  const int aoff1 = rA1*HC + sbA1;
  const int cB0 = cA0, cB1 = cA1;
  const int boff0 = aoff0, boff1 = aoff1;      // same mapping, B base differs
  const short* Ag = A  + (size_t)m0*HC;
  const short* Bg = Bw + (size_t)n0*HC;
  f32x4 acc[4][4] = {};

#pragma unroll
  for (int pk = 0; pk < 2; ++pk) {
    gll16(Ag + (size_t)(aoff0 + pk*32), (void*)(As + pk*4096 + cA0*8));
    gll16(Ag + (size_t)(aoff1 + pk*32), (void*)(As + pk*4096 + cA1*8));
    gll16(Bg + (size_t)(boff0 + pk*32), (void*)(Bs + pk*4096 + cB0*8));
    gll16(Bg + (size_t)(boff1 + pk*32), (void*)(Bs + pk*4096 + cB1*8));
  }

#pragma unroll 1
  for (int kt = 0; kt < 21; kt += 3) {
    bt_ktile<4,true,0>(kt,   As, Bs, Ag, Bg, wr, wc, quad, lc,
                       aoff0, aoff1, boff0, boff1, cA0, cA1, cB0, cB1, acc);
    bt_ktile<4,true,1>(kt+1, As, Bs, Ag, Bg, wr, wc, quad, lc,
                       aoff0, aoff1, boff0, boff1, cA0, cA1, cB0, cB1, acc);
    bt_ktile<4,true,2>(kt+2, As, Bs, Ag, Bg, wr, wc, quad, lc,
                       aoff0, aoff1, boff0, boff1, cA0, cA1, cB0, cB1, acc);
  }
  bt_ktile<4,true ,0>(21, As, Bs, Ag, Bg, wr, wc, quad, lc,
                      aoff0, aoff1, boff0, boff1, cA0, cA1, cB0, cB1, acc);  // stages T23
  bt_ktile<4,false,1>(22, As, Bs, Ag, Bg, wr, wc, quad, lc,
                      aoff0, aoff1, boff0, boff1, cA0, cA1, cB0, cB1, acc);
  bt_ktile<0,false,2>(23, As, Bs, Ag, Bg, wr, wc, quad, lc,
                      aoff0, aoff1, boff0, boff1, cA0, cA1, cB0, cB1, acc);

#pragma unroll
  for (int mt = 0; mt < 4; ++mt)
#pragma unroll
    for (int nt = 0; nt < 4; ++nt)
#pragma unroll
      for (int r = 0; r < 4; ++r) {
        const int row = m0 + wr*64 + mt*16 + quad*4 + r;
        const int col = n0 + wc*64 + nt*16 + lc;
        C[(size_t)row*HC + col] = acc[mt][nt][r];
      }
}

// ---------------- flash attention: 128 q-rows/block, 64-key chunks ----------
// R9 structure; R13: XCD-grouped block swizzle (all 8 q-tiles of each bh on
// one XCD -> per-XCD K/V working set 12*256KB = 3MB fits the 4MB L2).
// R16: s_setprio(1) around both MFMA clusters (T5; m191 +4-7% on attn —
// waves here drift independently between staging barriers, the regime where
// setprio pays; zero numerics impact).
__global__ __launch_bounds__(256, 3) void attn_kernel(const short* __restrict__ Qb,
                                                      const short* __restrict__ Kb,
                                                      const short* __restrict__ Vtb,
                                                      short* __restrict__ AOb) {
  const int raw = blockIdx.x;
  const int blk = (raw & 7)*96 + (raw >> 3);   // bijective on [0,768)
  const int qt = blk & 7, bh = blk >> 3;
  const int b = bh / HH, h = bh % HH;
  const int tid = threadIdx.x, w = tid >> 6, lane = tid & 63;
  const int quad = lane >> 4, lc = lane & 15;

  __shared__ short Ks [64][72];      // K chunk: row=key(natural), padded
  __shared__ short Vts[64][72];      // V chunk: row=d, cols=64 keys permuted
  __shared__ short Ps [4][32][72];   // per-wave P stash (32 q-rows), permuted keys

  // Q A-fragments: A[m=lane&15][k=quad*8+j]; wave rows qt*128 + w*32 + mt*16
  bf16x8 aq[2][2];
#pragma unroll
  for (int mt = 0; mt < 2; ++mt) {
    const int mrow = qt*128 + w*32 + mt*16 + lc;
    aq[mt][0] = *(const bf16x8*)(Qb + ((size_t)bh*HN + mrow)*HD + quad*8);
    aq[mt][1] = *(const bf16x8*)(Qb + ((size_t)bh*HN + mrow)*HD + 32 + quad*8);
  }

  const short* kbh = Kb  + (size_t)bh*HN*HD;
  const short* vbh = Vtb + (size_t)bh*HD*HN;

  f32x4 oacc[2][4] = {};
  float l_i[2][4] = {};

  // staging regs: c = i*256+tid in [0,512); row=c>>3 in [0,64), cb=c&7
  bf16x8 gk[2], gv[2];
#pragma unroll
  for (int i = 0; i < 2; ++i) {
    const int c = i*256 + tid;
    gk[i] = *(const bf16x8*)(kbh + (size_t)(c >> 3)*HD + (c & 7)*8);
    gv[i] = *(const bf16x8*)(vbh + (size_t)(c >> 3)*HN + (c & 7)*8);
  }
#pragma unroll
  for (int i = 0; i < 2; ++i) {
    const int c = i*256 + tid;
    *(bf16x8*)(&Ks [c >> 3][(c & 7)*8]) = gk[i];
    *(bf16x8*)(&Vts[c >> 3][(c & 7)*8]) = gv[i];
  }
  __syncthreads();

  const float LOG2E = 1.44269504f;
  const float MB2   = 8.0f * 1.44269504f;   // fixed max * log2(e)

  for (int ck = 0; ck < 16; ++ck) {
    // prefetch chunk ck+1 into registers (overlaps with compute below)
    if (ck < 15) {
      const int nn0 = (ck + 1)*64;
#pragma unroll
      for (int i = 0; i < 2; ++i) {
        const int c = i*256 + tid;
        gk[i] = *(const bf16x8*)(kbh + (size_t)(nn0 + (c >> 3))*HD + (c & 7)*8);
        gv[i] = *(const bf16x8*)(vbh + (size_t)(c >> 3)*HN + nn0 + (c & 7)*8);
      }
    }

    // S = Q K^T : 16 MFMAs (2 m-tiles x 2 kk x 4 nt)
    f32x4 sacc[2][4] = {};
    __builtin_amdgcn_s_setprio(1);
#pragma unroll
    for (int kk = 0; kk < 2; ++kk)
#pragma unroll
      for (int nt = 0; nt < 4; ++nt) {
        bf16x8 bk = *(const bf16x8*)(&Ks[nt*16 + lc][kk*32 + quad*8]);
#pragma unroll
        for (int mt = 0; mt < 2; ++mt)
          sacc[mt][nt] = mfma16(aq[mt][kk], bk, sacc[mt][nt]);
      }
    __builtin_amdgcn_s_setprio(0);

    // fixed-max softmax + P stash (C->A relayout, ds_write_b64 per row)
#pragma unroll
    for (int mt = 0; mt < 2; ++mt)
#pragma unroll
      for (int r = 0; r < 4; ++r) {
        float ps[4];
#pragma unroll
        for (int nt = 0; nt < 4; ++nt) {
          ps[nt] = fast_exp2(__builtin_fmaf(sacc[mt][nt][r], LOG2E, -MB2));
          sacc[mt][nt][r] = ps[nt];
        }
        l_i[mt][r] += (ps[0] + ps[1]) + (ps[2] + ps[3]);
        uint2 pk;
        pk.x = pack_bf16_rne(ps[0], ps[1]);
        pk.y = pack_bf16_rne(ps[2], ps[3]);
        *(uint2*)(&Ps[w][mt*16 + quad*4 + r][lc*4]) = pk;
      }

    // O += P V : 16 MFMAs (A from Ps, B from Vts; both in permuted key space)
    __builtin_amdgcn_s_setprio(1);
#pragma unroll
    for (int kk = 0; kk < 2; ++kk) {
      bf16x8 ap[2];
#pragma unroll
      for (int mt = 0; mt < 2; ++mt)
        ap[mt] = *(const bf16x8*)(&Ps[w][mt*16 + lc][kk*32 + quad*8]);
#pragma unroll
      for (int nt2 = 0; nt2 < 4; ++nt2) {
        bf16x8 bv = *(const bf16x8*)(&Vts[nt2*16 + lc][kk*32 + quad*8]);
#pragma unroll
        for (int mt = 0; mt < 2; ++mt)
          oacc[mt][nt2] = mfma16(ap[mt], bv, oacc[mt][nt2]);
      }
    }
    __builtin_amdgcn_s_setprio(0);

    if (ck < 15) {
      __syncthreads();   // all waves done reading Ks/Vts
#pragma unroll
      for (int i = 0; i < 2; ++i) {
        const int c = i*256 + tid;
        *(bf16x8*)(&Ks [c >> 3][(c & 7)*8]) = gk[i];
        *(bf16x8*)(&Vts[c >> 3][(c & 7)*8]) = gv[i];
      }
      __syncthreads();
    }
  }

  // epilogue: reduce l across the 16 lanes of each quad, then scale & store
#pragma unroll
  for (int mt = 0; mt < 2; ++mt)
#pragma unroll
    for (int r = 0; r < 4; ++r) {
      float l = l_i[mt][r];
#pragma unroll
      for (int off = 1; off < 16; off <<= 1) l += __shfl_xor(l, off);
      const float rl = 1.0f / l;
      const int row = qt*128 + w*32 + mt*16 + quad*4 + r;
#pragma unroll
      for (int nt2 = 0; nt2 < 4; ++nt2) {
        const int d = nt2*16 + lc;
        AOb[((size_t)(b*HN + row))*HC + h*HD + d] = f2bf(oacc[mt][nt2][r] * rl);
      }
    }
}

// ---------------- launch ----------------
extern "C" void kernel_launch(void* const* d_in, const int* in_sizes, int n_in,
                              void* d_out, int out_size, void* d_ws, size_t ws_size,
                              hipStream_t stream) {
  const float* x     = (const float*)d_in[0];
  const float* wqkv  = (const float*)d_in[1];
  const float* wproj = (const float*)d_in[2];
  float* out = (float*)d_out;

  char* ws = (char*)d_ws;
  size_t off = 0;
  auto alloc = [&](size_t bytes) -> void* {
    void* p = ws + off; off += (bytes + 255) & ~(size_t)255; return p;
  };
  short* xb     = (short*)alloc((size_t)ROWS*HC*2);        // 12.6 MB
  short* wqkvb  = (short*)alloc((size_t)3*HC*HC*2);        //  3.5 MB
  short* wprojb = (short*)alloc((size_t)HC*HC*2);          //  1.2 MB
  short* Qb     = (short*)alloc((size_t)BH*HN*HD*2);       // 12.6 MB
  short* Kb     = (short*)alloc((size_t)BH*HN*HD*2);       // 12.6 MB
  short* Vtb    = (short*)alloc((size_t)BH*HD*HN*2);       // 12.6 MB
  short* AOb    = (short*)alloc((size_t)ROWS*HC*2);        // 12.6 MB  (~68 MB total)

  { const int n0 = ROWS*HC/4, n1 = 3*HC*HC/4, n2 = HC*HC/4;
    const int tot = n0 + n1 + n2;
    cvt3_kernel<<<(tot + 255)/256, 256, 0, stream>>>(x, xb, n0, wqkv, wqkvb, n1,
                                                     wproj, wprojb, n2); }

  // 576 = 32 m-blocks x 18 n-blocks, XCD-swizzled inside the kernel
  gemm_qkv<<<dim3(576), 512, 0, stream>>>(xb, wqkvb, Qb, Kb, Vtb);
  attn_kernel<<<BH*8, 256, 0, stream>>>(Qb, Kb, Vtb, AOb);
  // 384 = 64 m-blocks x 6 n-blocks, XCD-swizzled inside the kernel
  gemm_bt_f32<<<dim3(384), 256, 0, stream>>>(AOb, wprojb, out);
}

// Round 9
// 181.463 us; speedup vs baseline: 1.6508x; 1.0262x over previous
//
#include <hip/hip_runtime.h>
#include <stdint.h>
#include <stddef.h>

// Problem constants
#define HB 8
#define HN 1024
#define HC 768
#define HH 12
#define HD 64
#define ROWS (HB*HN)      // 8192
#define BH (HB*HH)        // 96

using s16x4  = __attribute__((ext_vector_type(4))) short;
using bf16x8 = __attribute__((ext_vector_type(8))) short;
using f32x4  = __attribute__((ext_vector_type(4))) float;

__device__ __forceinline__ short f2bf(float f) {
  union { float f; uint32_t u; } c; c.f = f;
  uint32_t u = c.u;
  uint32_t r = (u + 0x7fffu + ((u >> 16) & 1u)) >> 16;   // RNE
  return (short)r;
}
__device__ __forceinline__ float bf2f(short s) {
  union { uint32_t u; float f; } c; c.u = ((uint32_t)(uint16_t)s) << 16;
  return c.f;
}
// pack two f32 -> {bf16(a) | bf16(b)<<16} with RNE, via v_perm_b32
__device__ __forceinline__ uint32_t pack_bf16_rne(float a, float b) {
  union { float f; uint32_t u; } ca, cb; ca.f = a; cb.f = b;
  uint32_t ra = ca.u + 0x7fffu + ((ca.u >> 16) & 1u);
  uint32_t rb = cb.u + 0x7fffu + ((cb.u >> 16) & 1u);
  return __builtin_amdgcn_perm(rb, ra, 0x07060302);  // {rb[31:16], ra[31:16]}
}
__device__ __forceinline__ float fast_exp2(float x) {
#if __has_builtin(__builtin_amdgcn_exp2f)
  return __builtin_amdgcn_exp2f(x);
#else
  return exp2f(x);
#endif
}
__device__ __forceinline__ f32x4 mfma16(bf16x8 a, bf16x8 b, f32x4 c) {
  return __builtin_amdgcn_mfma_f32_16x16x32_bf16(a, b, c, 0, 0, 0);
}
// async global->LDS, 16B per lane. LDS dest MUST be wave-uniform base + lane*16.
__device__ __forceinline__ void gll16(const void* g, void* l) {
  __builtin_amdgcn_global_load_lds((const __attribute__((address_space(1))) void*)g,
                                   (__attribute__((address_space(3))) void*)l,
                                   16, 0, 0);
}

// ---------------- fused f32 -> bf16 convert for all 3 inputs ----------------
// (R16: restored — R15's in-GEMM x conversion spilled to scratch: WRITE_SIZE
// 37->264MB, MfmaUtil 23->6%. Keep the standalone pass.)
__global__ void cvt3_kernel(const float* __restrict__ x,  short* __restrict__ xb,  int n0,
                            const float* __restrict__ wq, short* __restrict__ wqb, int n1,
                            const float* __restrict__ wp, short* __restrict__ wpb, int n2) {
  int i = blockIdx.x * 256 + threadIdx.x;        // index in float4 units
  const float* in; short* out;
  if (i < n0)            { in = x;  out = xb;  }
  else if (i < n0 + n1)  { i -= n0; in = wq; out = wqb; }
  else if (i < n0 + n1 + n2) { i -= n0 + n1; in = wp; out = wpb; }
  else return;
  float4 v = ((const float4*)in)[i];
  s16x4 o;
  o.x = f2bf(v.x); o.y = f2bf(v.y); o.z = f2bf(v.z); o.w = f2bf(v.w);
  ((s16x4*)out)[i] = o;
}

// ---------------- GEMM 1: qkv = x*Wqkv^T ------------------------------------
// R11 pipeline (proven): BM=256 BN=128 BK=32, 512 thr (8 waves, 4Mx2N),
// 3 LDS slots, 2-deep staging, one barrier + one vmcnt(3) per K-tile.
// R12: v-epilogue writes Vtb DIRECTLY (key-permuted transpose via LDS reuse).
template<int VM, bool STG, int SLOT>
__device__ __forceinline__ void qkv_ktile(
    int kt, short* sA, short* sB,
    const short* Ag, const short* Bg,
    int wr, int wc, int quad, int lc,
    int aoff0, int aoff1, int boff0,      // per-thread source offsets (row*HC+swz-col)
    int cA0, int cA1, int cB0,            // per-thread LDS chunk ids
    f32x4 (&acc)[4][4])
{
  // T(kt) landed for THIS wave; barrier makes it true for ALL waves.
  if constexpr (VM == 3) asm volatile("s_waitcnt vmcnt(3)" ::: "memory");
  else                   asm volatile("s_waitcnt vmcnt(0)" ::: "memory");
  __builtin_amdgcn_s_barrier();
  // After the barrier every wave finished iteration kt-1 (incl. its ds_reads
  // of slot (kt-1)%3) -> safe to stage kt+2 into that slot.
  if constexpr (STG) {
    constexpr int DST = (SLOT + 2) % 3;
    const int kcol = (kt + 2) * 32;
    short* dA = sA + DST*8192;
    short* dB = sB + DST*4096;
    gll16(Ag + (size_t)(aoff0 + kcol), (void*)(dA + cA0*8));
    gll16(Ag + (size_t)(aoff1 + kcol), (void*)(dA + cA1*8));
    gll16(Bg + (size_t)(boff0 + kcol), (void*)(dB + cB0*8));
  }
  const short* sa = sA + SLOT*8192;
  const short* sb = sB + SLOT*4096;
  bf16x8 af[4], bfr[4];
#pragma unroll
  for (int mt = 0; mt < 4; ++mt) {
    const int rA = wr*64 + mt*16 + lc;
    af[mt] = *(const bf16x8*)(sa + rA*32 + (quad ^ ((rA >> 1) & 3))*8);
  }
#pragma unroll
  for (int nt = 0; nt < 4; ++nt) {
    const int rB = wc*64 + nt*16 + lc;
    bfr[nt] = *(const bf16x8*)(sb + rB*32 + (quad ^ ((rB >> 1) & 3))*8);
  }
  __builtin_amdgcn_s_setprio(1);
#pragma unroll
  for (int mt = 0; mt < 4; ++mt)
#pragma unroll
    for (int nt = 0; nt < 4; ++nt)
      acc[mt][nt] = mfma16(af[mt], bfr[nt], acc[mt][nt]);
  __builtin_amdgcn_s_setprio(0);
}

__global__ __launch_bounds__(512, 4) void gemm_qkv(const short* __restrict__ A,
                                                   const short* __restrict__ Bw,
                                                   short* __restrict__ Qb,
                                                   short* __restrict__ Kb,
                                                   short* __restrict__ Vtb) {
  __shared__ short SMEM[3*256*32 + 3*128*32];   // 72 KiB, reused by v-epilogue
  short* As = SMEM;                 // 3 x [256][32]
  short* Bs = SMEM + 3*256*32;      // 3 x [128][32]
  // XCD-bijective swizzle: 576 wgs = 8 XCDs x 72 (4 m-panels x 18 n) each.
  const int wg = blockIdx.x;
  const int swz = (wg & 7)*72 + (wg >> 3);
  const int by = swz / 18, bx = swz % 18;
  const int m0 = by*256, n0 = bx*128;
  const int tid = threadIdx.x;
  const int lane = tid & 63, w = tid >> 6, quad = lane >> 4, lc = lane & 15;
  const int wr = w >> 1, wc = w & 1;           // 4 x 2 wave grid
  // staging: A tile 256x32 = 1024 16B-chunks (2/thread); B 128x32 = 512 (1/thread)
  // chunk c: r = c>>2, cb = c&3; source col pre-swizzled cb ^ ((r>>1)&3)
  const int cA0 = tid,        rA0 = cA0 >> 2, sbA0 = ((cA0 & 3) ^ ((rA0 >> 1) & 3))*8;
  const int cA1 = 512 + tid,  rA1 = cA1 >> 2, sbA1 = ((cA1 & 3) ^ ((rA1 >> 1) & 3))*8;
  const int cB0 = tid,        rB0 = cB0 >> 2, sbB0 = ((cB0 & 3) ^ ((rB0 >> 1) & 3))*8;
  const int aoff0 = rA0*HC + sbA0;
  const int aoff1 = rA1*HC + sbA1;
  const int boff0 = rB0*HC + sbB0;
  const short* Ag = A  + (size_t)m0*HC;
  const short* Bg = Bw + (size_t)n0*HC;
  f32x4 acc[4][4] = {};

  // prologue: stage K-tiles 0 and 1 (FIFO order: T0's 3 loads, then T1's 3)
#pragma unroll
  for (int pk = 0; pk < 2; ++pk) {
    gll16(Ag + (size_t)(aoff0 + pk*32), (void*)(As + pk*8192 + cA0*8));
    gll16(Ag + (size_t)(aoff1 + pk*32), (void*)(As + pk*8192 + cA1*8));
    gll16(Bg + (size_t)(boff0 + pk*32), (void*)(Bs + pk*4096 + cB0*8));
  }

  // main loop: 24 K-tiles, unrolled by 3 so the slot index is compile-time
#pragma unroll 1
  for (int kt = 0; kt < 21; kt += 3) {
    qkv_ktile<3,true,0>(kt,   As, Bs, Ag, Bg, wr, wc, quad, lc,
                        aoff0, aoff1, boff0, cA0, cA1, cB0, acc);
    qkv_ktile<3,true,1>(kt+1, As, Bs, Ag, Bg, wr, wc, quad, lc,
                        aoff0, aoff1, boff0, cA0, cA1, cB0, acc);
    qkv_ktile<3,true,2>(kt+2, As, Bs, Ag, Bg, wr, wc, quad, lc,
                        aoff0, aoff1, boff0, cA0, cA1, cB0, acc);
  }
  qkv_ktile<3,true ,0>(21, As, Bs, Ag, Bg, wr, wc, quad, lc,
                       aoff0, aoff1, boff0, cA0, cA1, cB0, acc);   // stages T23
  qkv_ktile<3,false,1>(22, As, Bs, Ag, Bg, wr, wc, quad, lc,
                       aoff0, aoff1, boff0, cA0, cA1, cB0, acc);
  qkv_ktile<0,false,2>(23, As, Bs, Ag, Bg, wr, wc, quad, lc,
                       aoff0, aoff1, boff0, cA0, cA1, cB0, acc);

  // epilogue (C/D: col=nt*16+lc, row=quad*4+r); per-wave 64-col group = 1 head
  const int cg = n0 + wc*64;
  const int t = cg / HC;                // 0=q, 1=k, 2=v (block-uniform: n0 % 128 == 0)
  const int h = (cg % HC) / HD;
  if (t < 2) {
    short* outp = (t == 0) ? Qb : Kb;
    const float sc = (t == 0) ? 0.125f : 1.0f;   // SCALE = 64^-0.5 for q
#pragma unroll
    for (int i = 0; i < 4; ++i)
#pragma unroll
      for (int r = 0; r < 4; ++r) {
        float s1 = (acc[i][0][r] + acc[i][1][r]) + (acc[i][2][r] + acc[i][3][r]);
        float s2 = acc[i][0][r]*acc[i][0][r];
        s2 = __builtin_fmaf(acc[i][1][r], acc[i][1][r], s2);
        s2 = __builtin_fmaf(acc[i][2][r], acc[i][2][r], s2);
        s2 = __builtin_fmaf(acc[i][3][r], acc[i][3][r], s2);
#pragma unroll
        for (int off = 1; off < 16; off <<= 1) {
          s1 += __shfl_xor(s1, off);
          s2 += __shfl_xor(s2, off);
        }
        const float mean = s1 * (1.0f/64.0f);
        const float var  = s2 * (1.0f/64.0f) - mean*mean;
        const float inv  = rsqrtf(var + 1e-5f) * sc;
        const int row = m0 + wr*64 + i*16 + quad*4 + r;
        const int b = row >> 10, n_in = row & 1023;
        short* rowp = outp + ((size_t)(b*HH + h)*HN + n_in)*HD;
#pragma unroll
        for (int nt = 0; nt < 4; ++nt)
          rowp[nt*16 + lc] = f2bf((acc[i][nt][r] - mean) * inv);
      }
  } else {
    // fused V-transpose: acc -> LDS (key-permuted, stride 268) -> Vtb.
    // Storage col c holds key k: c(k) = ((k&15)<<2)|(k>>4); inverse of
    // attn's perm(c) = (c&3)*16 + (c>>2)  [perm(c(k)) == k].
    short* vs = SMEM;                 // [2][64][268] = 34304 shorts <= 36864
    __syncthreads();                  // main-loop LDS fully consumed by all waves
    const int hd = wc;                // wave's head slot (0/1)
#pragma unroll
    for (int i = 0; i < 4; ++i)
#pragma unroll
      for (int nt = 0; nt < 4; ++nt)
#pragma unroll
        for (int r = 0; r < 4; ++r) {
          const int dd = nt*16 + lc;
          const int k  = i*16 + quad*4 + r;            // row within 64-group
          const int c  = ((k & 15) << 2) | (k >> 4);   // permuted col
          vs[(hd*64 + dd)*268 + wr*64 + c] = f2bf(acc[i][nt][r]);
        }
    __syncthreads();
    const int b = m0 >> 10, m0g = m0 & 1023;
#pragma unroll
    for (int it = 0; it < 8; ++it) {
      const int idx = it*512 + tid;        // [0,4096)
      const int h2 = idx >> 11;            // head slot 0/1
      const int rem = idx & 2047;
      const int dd = rem >> 5, c8 = rem & 31;
      const int habs = ((n0 + h2*64) - 1536) >> 6;     // absolute head
      const short* src = vs + (h2*64 + dd)*268 + c8*8; // 8B-aligned
      s16x4 lo = *(const s16x4*)(src);
      s16x4 hi = *(const s16x4*)(src + 4);
      bf16x8 vvv;
      vvv[0]=lo[0]; vvv[1]=lo[1]; vvv[2]=lo[2]; vvv[3]=lo[3];
      vvv[4]=hi[0]; vvv[5]=hi[1]; vvv[6]=hi[2]; vvv[7]=hi[3];
      *(bf16x8*)(Vtb + ((size_t)((b*HH + habs)*HD + dd))*HN + m0g + c8*8) = vvv;
    }
  }
}

// ---------------- GEMM 2: out = AO * Wproj^T (f32 out) ----------------------
// R14: R11 counted-vmcnt pipeline. BM=128 BN=128 BK=32, 256 thr (4 waves),
// 3 LDS slots = 48 KiB -> 3 blocks/CU; grid 384 co-resident, no tail.
template<int VM, bool STG, int SLOT>
__device__ __forceinline__ void bt_ktile(
    int kt, short* sA, short* sB,
    const short* Ag, const short* Bg,
    int wr, int wc, int quad, int lc,
    int aoff0, int aoff1, int boff0, int boff1,
    int cA0, int cA1, int cB0, int cB1,
    f32x4 (&acc)[4][4])
{
  if constexpr (VM == 4) asm volatile("s_waitcnt vmcnt(4)" ::: "memory");
  else                   asm volatile("s_waitcnt vmcnt(0)" ::: "memory");
  __builtin_amdgcn_s_barrier();
  if constexpr (STG) {
    constexpr int DST = (SLOT + 2) % 3;
    const int kcol = (kt + 2) * 32;
    short* dA = sA + DST*4096;
    short* dB = sB + DST*4096;
    gll16(Ag + (size_t)(aoff0 + kcol), (void*)(dA + cA0*8));
    gll16(Ag + (size_t)(aoff1 + kcol), (void*)(dA + cA1*8));
    gll16(Bg + (size_t)(boff0 + kcol), (void*)(dB + cB0*8));
    gll16(Bg + (size_t)(boff1 + kcol), (void*)(dB + cB1*8));
  }
  const short* sa = sA + SLOT*4096;
  const short* sb = sB + SLOT*4096;
  bf16x8 af[4], bfr[4];
#pragma unroll
  for (int mt = 0; mt < 4; ++mt) {
    const int rA = wr*64 + mt*16 + lc;
    af[mt] = *(const bf16x8*)(sa + rA*32 + (quad ^ ((rA >> 1) & 3))*8);
  }
#pragma unroll
  for (int nt = 0; nt < 4; ++nt) {
    const int rB = wc*64 + nt*16 + lc;
    bfr[nt] = *(const bf16x8*)(sb + rB*32 + (quad ^ ((rB >> 1) & 3))*8);
  }
  __builtin_amdgcn_s_setprio(1);
#pragma unroll
  for (int mt = 0; mt < 4; ++mt)
#pragma unroll
    for (int nt = 0; nt < 4; ++nt)
      acc[mt][nt] = mfma16(af[mt], bfr[nt], acc[mt][nt]);
  __builtin_amdgcn_s_setprio(0);
}

__global__ __launch_bounds__(256, 3) void gemm_bt_f32(const short* __restrict__ A,
                                                      const short* __restrict__ Bw,
                                                      float* __restrict__ C) {
  __shared__ short As[3*128*32];   // 24 KiB
  __shared__ short Bs[3*128*32];   // 24 KiB
  // XCD swizzle: 384 wgs = 8 XCDs x 48 (8 m-panels x 6 n) each.
  const int wg = blockIdx.x;
  const int swz = (wg & 7)*48 + (wg >> 3);
  const int by = swz / 6, bx = swz % 6;
  const int m0 = by*128, n0 = bx*128;
  const int tid = threadIdx.x;
  const int lane = tid & 63, w = tid >> 6, quad = lane >> 4, lc = lane & 15;
  const int wr = w >> 1, wc = w & 1;           // 2 x 2 wave grid
  const int cA0 = tid,        rA0 = cA0 >> 2, sbA0 = ((cA0 & 3) ^ ((rA0 >> 1) & 3))*8;
  const int cA1 = 256 + tid,  rA1 = cA1 >> 2, sbA1 = ((cA1 & 3) ^ ((rA1 >> 1) & 3))*8;
  const int aoff0 = rA0*HC + sbA0;
  const int aoff1 = rA1*HC + sbA1;
  const int cB0 = cA0, cB1 = cA1;
  const int boff0 = aoff0, boff1 = aoff1;      // same mapping, B base differs
  const short* Ag = A  + (size_t)m0*HC;
  const short* Bg = Bw + (size_t)n0*HC;
  f32x4 acc[4][4] = {};

#pragma unroll
  for (int pk = 0; pk < 2; ++pk) {
    gll16(Ag + (size_t)(aoff0 + pk*32), (void*)(As + pk*4096 + cA0*8));
    gll16(Ag + (size_t)(aoff1 + pk*32), (void*)(As + pk*4096 + cA1*8));
    gll16(Bg + (size_t)(boff0 + pk*32), (void*)(Bs + pk*4096 + cB0*8));
    gll16(Bg + (size_t)(boff1 + pk*32), (void*)(Bs + pk*4096 + cB1*8));
  }

#pragma unroll 1
  for (int kt = 0; kt < 21; kt += 3) {
    bt_ktile<4,true,0>(kt,   As, Bs, Ag, Bg, wr, wc, quad, lc,
                       aoff0, aoff1, boff0, boff1, cA0, cA1, cB0, cB1, acc);
    bt_ktile<4,true,1>(kt+1, As, Bs, Ag, Bg, wr, wc, quad, lc,
                       aoff0, aoff1, boff0, boff1, cA0, cA1, cB0, cB1, acc);
    bt_ktile<4,true,2>(kt+2, As, Bs, Ag, Bg, wr, wc, quad, lc,
                       aoff0, aoff1, boff0, boff1, cA0, cA1, cB0, cB1, acc);
  }
  bt_ktile<4,true ,0>(21, As, Bs, Ag, Bg, wr, wc, quad, lc,
                      aoff0, aoff1, boff0, boff1, cA0, cA1, cB0, cB1, acc);  // stages T23
  bt_ktile<4,false,1>(22, As, Bs, Ag, Bg, wr, wc, quad, lc,
                      aoff0, aoff1, boff0, boff1, cA0, cA1, cB0, cB1, acc);
  bt_ktile<0,false,2>(23, As, Bs, Ag, Bg, wr, wc, quad, lc,
                      aoff0, aoff1, boff0, boff1, cA0, cA1, cB0, cB1, acc);

#pragma unroll
  for (int mt = 0; mt < 4; ++mt)
#pragma unroll
    for (int nt = 0; nt < 4; ++nt)
#pragma unroll
      for (int r = 0; r < 4; ++r) {
        const int row = m0 + wr*64 + mt*16 + quad*4 + r;
        const int col = n0 + wc*64 + nt*16 + lc;
        C[(size_t)row*HC + col] = acc[mt][nt][r];
      }
}

// ---------------- flash attention: 128 q-rows/block, 64-key chunks ----------
// R9 structure; R13: XCD-grouped block swizzle. R17: double-buffered K/V LDS
// -> ONE barrier per chunk (was 2): compute reads buf[p] while end-of-chunk
// writes fill buf[p^1] (its readers finished at chunk ck-1's barrier).
// Ps re-laid to stride 64 + 16B-unit XOR swizzle (phys_unit = log_unit ^
// (row&7), applied on both write and read) to fit 3-blocks/CU LDS budget
// (53248 B <= 54613). Values bit-identical; only LDS addresses changed.
// (R16's attn setprio reverted: −5.6 us — all 4 waves are barrier-lockstep,
// so raising prio during MFMA only starves co-resident blocks' staging.)
__global__ __launch_bounds__(256, 3) void attn_kernel(const short* __restrict__ Qb,
                                                      const short* __restrict__ Kb,
                                                      const short* __restrict__ Vtb,
                                                      short* __restrict__ AOb) {
  const int raw = blockIdx.x;
  const int blk = (raw & 7)*96 + (raw >> 3);   // bijective on [0,768)
  const int qt = blk & 7, bh = blk >> 3;
  const int b = bh / HH, h = bh % HH;
  const int tid = threadIdx.x, w = tid >> 6, lane = tid & 63;
  const int quad = lane >> 4, lc = lane & 15;

  __shared__ short Ks [2][64][72];   // K chunk dbuf: row=key(natural), padded
  __shared__ short Vts[2][64][72];   // V chunk dbuf: row=d, cols=64 keys permuted
  __shared__ short Ps [4][32][64];   // per-wave P stash, XOR-swizzled 16B units

  // Q A-fragments: A[m=lane&15][k=quad*8+j]; wave rows qt*128 + w*32 + mt*16
  bf16x8 aq[2][2];
#pragma unroll
  for (int mt = 0; mt < 2; ++mt) {
    const int mrow = qt*128 + w*32 + mt*16 + lc;
    aq[mt][0] = *(const bf16x8*)(Qb + ((size_t)bh*HN + mrow)*HD + quad*8);
    aq[mt][1] = *(const bf16x8*)(Qb + ((size_t)bh*HN + mrow)*HD + 32 + quad*8);
  }

  const short* kbh = Kb  + (size_t)bh*HN*HD;
  const short* vbh = Vtb + (size_t)bh*HD*HN;

  f32x4 oacc[2][4] = {};
  float l_i[2][4] = {};

  // staging regs: c = i*256+tid in [0,512); row=c>>3 in [0,64), cb=c&7
  bf16x8 gk[2], gv[2];
#pragma unroll
  for (int i = 0; i < 2; ++i) {
    const int c = i*256 + tid;
    gk[i] = *(const bf16x8*)(kbh + (size_t)(c >> 3)*HD + (c & 7)*8);
    gv[i] = *(const bf16x8*)(vbh + (size_t)(c >> 3)*HN + (c & 7)*8);
  }
#pragma unroll
  for (int i = 0; i < 2; ++i) {
    const int c = i*256 + tid;
    *(bf16x8*)(&Ks [0][c >> 3][(c & 7)*8]) = gk[i];
    *(bf16x8*)(&Vts[0][c >> 3][(c & 7)*8]) = gv[i];
  }
  __syncthreads();

  const float LOG2E = 1.44269504f;
  const float MB2   = 8.0f * 1.44269504f;   // fixed max * log2(e)

  for (int ck = 0; ck < 16; ++ck) {
    const int p = ck & 1;
    // prefetch chunk ck+1 into registers (overlaps with compute below)
    if (ck < 15) {
      const int nn0 = (ck + 1)*64;
#pragma unroll
      for (int i = 0; i < 2; ++i) {
        const int c = i*256 + tid;
        gk[i] = *(const bf16x8*)(kbh + (size_t)(nn0 + (c >> 3))*HD + (c & 7)*8);
        gv[i] = *(const bf16x8*)(vbh + (size_t)(c >> 3)*HN + nn0 + (c & 7)*8);
      }
    }

    // S = Q K^T : 16 MFMAs (2 m-tiles x 2 kk x 4 nt)
    f32x4 sacc[2][4] = {};
#pragma unroll
    for (int kk = 0; kk < 2; ++kk)
#pragma unroll
      for (int nt = 0; nt < 4; ++nt) {
        bf16x8 bk = *(const bf16x8*)(&Ks[p][nt*16 + lc][kk*32 + quad*8]);
#pragma unroll
        for (int mt = 0; mt < 2; ++mt)
          sacc[mt][nt] = mfma16(aq[mt][kk], bk, sacc[mt][nt]);
      }

    // fixed-max softmax + P stash (C->A relayout; swizzled 16B units)
#pragma unroll
    for (int mt = 0; mt < 2; ++mt)
#pragma unroll
      for (int r = 0; r < 4; ++r) {
        float ps[4];
#pragma unroll
        for (int nt = 0; nt < 4; ++nt) {
          ps[nt] = fast_exp2(__builtin_fmaf(sacc[mt][nt][r], LOG2E, -MB2));
          sacc[mt][nt][r] = ps[nt];
        }
        l_i[mt][r] += (ps[0] + ps[1]) + (ps[2] + ps[3]);
        uint2 pk;
        pk.x = pack_bf16_rne(ps[0], ps[1]);
        pk.y = pack_bf16_rne(ps[2], ps[3]);
        const int prow = mt*16 + quad*4 + r;
        const int unit = (lc >> 1) ^ (prow & 7);     // 16B-unit XOR swizzle
        *(uint2*)(&Ps[w][prow][unit*8 + (lc & 1)*4]) = pk;
      }

    // O += P V : 16 MFMAs (A from Ps, B from Vts; both in permuted key space)
#pragma unroll
    for (int kk = 0; kk < 2; ++kk) {
      bf16x8 ap[2];
#pragma unroll
      for (int mt = 0; mt < 2; ++mt) {
        const int arow = mt*16 + lc;
        ap[mt] = *(const bf16x8*)(&Ps[w][arow][((kk*4 + quad) ^ (arow & 7))*8]);
      }
#pragma unroll
      for (int nt2 = 0; nt2 < 4; ++nt2) {
        bf16x8 bv = *(const bf16x8*)(&Vts[p][nt2*16 + lc][kk*32 + quad*8]);
#pragma unroll
        for (int mt = 0; mt < 2; ++mt)
          oacc[mt][nt2] = mfma16(ap[mt], bv, oacc[mt][nt2]);
      }
    }

    if (ck < 15) {
      // write chunk ck+1 into the other buffer (its readers are past ck-1's
      // barrier), then ONE barrier so next chunk may read it.
#pragma unroll
      for (int i = 0; i < 2; ++i) {
        const int c = i*256 + tid;
        *(bf16x8*)(&Ks [p ^ 1][c >> 3][(c & 7)*8]) = gk[i];
        *(bf16x8*)(&Vts[p ^ 1][c >> 3][(c & 7)*8]) = gv[i];
      }
      __syncthreads();
    }
  }

  // epilogue: reduce l across the 16 lanes of each quad, then scale & store
#pragma unroll
  for (int mt = 0; mt < 2; ++mt)
#pragma unroll
    for (int r = 0; r < 4; ++r) {
      float l = l_i[mt][r];
#pragma unroll
      for (int off = 1; off < 16; off <<= 1) l += __shfl_xor(l, off);
      const float rl = 1.0f / l;
      const int row = qt*128 + w*32 + mt*16 + quad*4 + r;
#pragma unroll
      for (int nt2 = 0; nt2 < 4; ++nt2) {
        const int d = nt2*16 + lc;
        AOb[((size_t)(b*HN + row))*HC + h*HD + d] = f2bf(oacc[mt][nt2][r] * rl);
      }
    }
}

// ---------------- launch ----------------
extern "C" void kernel_launch(void* const* d_in, const int* in_sizes, int n_in,
                              void* d_out, int out_size, void* d_ws, size_t ws_size,
                              hipStream_t stream) {
  const float* x     = (const float*)d_in[0];
  const float* wqkv  = (const float*)d_in[1];
  const float* wproj = (const float*)d_in[2];
  float* out = (float*)d_out;

  char* ws = (char*)d_ws;
  size_t off = 0;
  auto alloc = [&](size_t bytes) -> void* {
    void* p = ws + off; off += (bytes + 255) & ~(size_t)255; return p;
  };
  short* xb     = (short*)alloc((size_t)ROWS*HC*2);        // 12.6 MB
  short* wqkvb  = (short*)alloc((size_t)3*HC*HC*2);        //  3.5 MB
  short* wprojb = (short*)alloc((size_t)HC*HC*2);          //  1.2 MB
  short* Qb     = (short*)alloc((size_t)BH*HN*HD*2);       // 12.6 MB
  short* Kb     = (short*)alloc((size_t)BH*HN*HD*2);       // 12.6 MB
  short* Vtb    = (short*)alloc((size_t)BH*HD*HN*2);       // 12.6 MB
  short* AOb    = (short*)alloc((size_t)ROWS*HC*2);        // 12.6 MB  (~68 MB total)

  { const int n0 = ROWS*HC/4, n1 = 3*HC*HC/4, n2 = HC*HC/4;
    const int tot = n0 + n1 + n2;
    cvt3_kernel<<<(tot + 255)/256, 256, 0, stream>>>(x, xb, n0, wqkv, wqkvb, n1,
                                                     wproj, wprojb, n2); }

  // 576 = 32 m-blocks x 18 n-blocks, XCD-swizzled inside the kernel
  gemm_qkv<<<dim3(576), 512, 0, stream>>>(xb, wqkvb, Qb, Kb, Vtb);
  attn_kernel<<<BH*8, 256, 0, stream>>>(Qb, Kb, Vtb, AOb);
  // 384 = 64 m-blocks x 6 n-blocks, XCD-swizzled inside the kernel
  gemm_bt_f32<<<dim3(384), 256, 0, stream>>>(AOb, wprojb, out);
}

// Round 12
// 181.300 us; speedup vs baseline: 1.6522x; 1.0009x over previous
//
#include <hip/hip_runtime.h>
#include <stdint.h>
#include <stddef.h>

// Problem constants
#define HB 8
#define HN 1024
#define HC 768
#define HH 12
#define HD 64
#define ROWS (HB*HN)      // 8192
#define BH (HB*HH)        // 96

using s16x4  = __attribute__((ext_vector_type(4))) short;
using bf16x8 = __attribute__((ext_vector_type(8))) short;
using f32x4  = __attribute__((ext_vector_type(4))) float;

__device__ __forceinline__ short f2bf(float f) {
  union { float f; uint32_t u; } c; c.f = f;
  uint32_t u = c.u;
  uint32_t r = (u + 0x7fffu + ((u >> 16) & 1u)) >> 16;   // RNE
  return (short)r;
}
__device__ __forceinline__ float bf2f(short s) {
  union { uint32_t u; float f; } c; c.u = ((uint32_t)(uint16_t)s) << 16;
  return c.f;
}
// pack two f32 -> {bf16(a) | bf16(b)<<16} with RNE, via v_perm_b32
__device__ __forceinline__ uint32_t pack_bf16_rne(float a, float b) {
  union { float f; uint32_t u; } ca, cb; ca.f = a; cb.f = b;
  uint32_t ra = ca.u + 0x7fffu + ((ca.u >> 16) & 1u);
  uint32_t rb = cb.u + 0x7fffu + ((cb.u >> 16) & 1u);
  return __builtin_amdgcn_perm(rb, ra, 0x07060302);  // {rb[31:16], ra[31:16]}
}
__device__ __forceinline__ float fast_exp2(float x) {
#if __has_builtin(__builtin_amdgcn_exp2f)
  return __builtin_amdgcn_exp2f(x);
#else
  return exp2f(x);
#endif
}
__device__ __forceinline__ f32x4 mfma16(bf16x8 a, bf16x8 b, f32x4 c) {
  return __builtin_amdgcn_mfma_f32_16x16x32_bf16(a, b, c, 0, 0, 0);
}
// async global->LDS, 16B per lane. LDS dest MUST be wave-uniform base + lane*16.
__device__ __forceinline__ void gll16(const void* g, void* l) {
  __builtin_amdgcn_global_load_lds((const __attribute__((address_space(1))) void*)g,
                                   (__attribute__((address_space(3))) void*)l,
                                   16, 0, 0);
}

// ---------------- fused f32 -> bf16 convert for all 3 inputs ----------------
__global__ void cvt3_kernel(const float* __restrict__ x,  short* __restrict__ xb,  int n0,
                            const float* __restrict__ wq, short* __restrict__ wqb, int n1,
                            const float* __restrict__ wp, short* __restrict__ wpb, int n2) {
  int i = blockIdx.x * 256 + threadIdx.x;        // index in float4 units
  const float* in; short* out;
  if (i < n0)            { in = x;  out = xb;  }
  else if (i < n0 + n1)  { i -= n0; in = wq; out = wqb; }
  else if (i < n0 + n1 + n2) { i -= n0 + n1; in = wp; out = wpb; }
  else return;
  float4 v = ((const float4*)in)[i];
  s16x4 o;
  o.x = f2bf(v.x); o.y = f2bf(v.y); o.z = f2bf(v.z); o.w = f2bf(v.w);
  ((s16x4*)out)[i] = o;
}

// ---------------- GEMM 1: qkv = x*Wqkv^T ------------------------------------
// R11 pipeline (proven): BM=256 BN=128 BK=32, 512 thr (8 waves, 4Mx2N),
// 3 LDS slots, 2-deep staging, one barrier + one vmcnt(3) per K-tile.
// R12: v-epilogue writes Vtb DIRECTLY (key-permuted transpose via LDS reuse).
template<int VM, bool STG, int SLOT>
__device__ __forceinline__ void qkv_ktile(
    int kt, short* sA, short* sB,
    const short* Ag, const short* Bg,
    int wr, int wc, int quad, int lc,
    int aoff0, int aoff1, int boff0,      // per-thread source offsets (row*HC+swz-col)
    int cA0, int cA1, int cB0,            // per-thread LDS chunk ids
    f32x4 (&acc)[4][4])
{
  // T(kt) landed for THIS wave; barrier makes it true for ALL waves.
  if constexpr (VM == 3) asm volatile("s_waitcnt vmcnt(3)" ::: "memory");
  else                   asm volatile("s_waitcnt vmcnt(0)" ::: "memory");
  __builtin_amdgcn_s_barrier();
  // After the barrier every wave finished iteration kt-1 (incl. its ds_reads
  // of slot (kt-1)%3) -> safe to stage kt+2 into that slot.
  if constexpr (STG) {
    constexpr int DST = (SLOT + 2) % 3;
    const int kcol = (kt + 2) * 32;
    short* dA = sA + DST*8192;
    short* dB = sB + DST*4096;
    gll16(Ag + (size_t)(aoff0 + kcol), (void*)(dA + cA0*8));
    gll16(Ag + (size_t)(aoff1 + kcol), (void*)(dA + cA1*8));
    gll16(Bg + (size_t)(boff0 + kcol), (void*)(dB + cB0*8));
  }
  const short* sa = sA + SLOT*8192;
  const short* sb = sB + SLOT*4096;
  bf16x8 af[4], bfr[4];
#pragma unroll
  for (int mt = 0; mt < 4; ++mt) {
    const int rA = wr*64 + mt*16 + lc;
    af[mt] = *(const bf16x8*)(sa + rA*32 + (quad ^ ((rA >> 1) & 3))*8);
  }
#pragma unroll
  for (int nt = 0; nt < 4; ++nt) {
    const int rB = wc*64 + nt*16 + lc;
    bfr[nt] = *(const bf16x8*)(sb + rB*32 + (quad ^ ((rB >> 1) & 3))*8);
  }
  __builtin_amdgcn_s_setprio(1);
#pragma unroll
  for (int mt = 0; mt < 4; ++mt)
#pragma unroll
    for (int nt = 0; nt < 4; ++nt)
      acc[mt][nt] = mfma16(af[mt], bfr[nt], acc[mt][nt]);
  __builtin_amdgcn_s_setprio(0);
}

__global__ __launch_bounds__(512, 4) void gemm_qkv(const short* __restrict__ A,
                                                   const short* __restrict__ Bw,
                                                   short* __restrict__ Qb,
                                                   short* __restrict__ Kb,
                                                   short* __restrict__ Vtb) {
  __shared__ short SMEM[3*256*32 + 3*128*32];   // 72 KiB, reused by v-epilogue
  short* As = SMEM;                 // 3 x [256][32]
  short* Bs = SMEM + 3*256*32;      // 3 x [128][32]
  // XCD-bijective swizzle: 576 wgs = 8 XCDs x 72 (4 m-panels x 18 n) each.
  const int wg = blockIdx.x;
  const int swz = (wg & 7)*72 + (wg >> 3);
  const int by = swz / 18, bx = swz % 18;
  const int m0 = by*256, n0 = bx*128;
  const int tid = threadIdx.x;
  const int lane = tid & 63, w = tid >> 6, quad = lane >> 4, lc = lane & 15;
  const int wr = w >> 1, wc = w & 1;           // 4 x 2 wave grid
  // staging: A tile 256x32 = 1024 16B-chunks (2/thread); B 128x32 = 512 (1/thread)
  // chunk c: r = c>>2, cb = c&3; source col pre-swizzled cb ^ ((r>>1)&3)
  const int cA0 = tid,        rA0 = cA0 >> 2, sbA0 = ((cA0 & 3) ^ ((rA0 >> 1) & 3))*8;
  const int cA1 = 512 + tid,  rA1 = cA1 >> 2, sbA1 = ((cA1 & 3) ^ ((rA1 >> 1) & 3))*8;
  const int cB0 = tid,        rB0 = cB0 >> 2, sbB0 = ((cB0 & 3) ^ ((rB0 >> 1) & 3))*8;
  const int aoff0 = rA0*HC + sbA0;
  const int aoff1 = rA1*HC + sbA1;
  const int boff0 = rB0*HC + sbB0;
  const short* Ag = A  + (size_t)m0*HC;
  const short* Bg = Bw + (size_t)n0*HC;
  f32x4 acc[4][4] = {};

  // prologue: stage K-tiles 0 and 1 (FIFO order: T0's 3 loads, then T1's 3)
#pragma unroll
  for (int pk = 0; pk < 2; ++pk) {
    gll16(Ag + (size_t)(aoff0 + pk*32), (void*)(As + pk*8192 + cA0*8));
    gll16(Ag + (size_t)(aoff1 + pk*32), (void*)(As + pk*8192 + cA1*8));
    gll16(Bg + (size_t)(boff0 + pk*32), (void*)(Bs + pk*4096 + cB0*8));
  }

  // main loop: 24 K-tiles, unrolled by 3 so the slot index is compile-time
#pragma unroll 1
  for (int kt = 0; kt < 21; kt += 3) {
    qkv_ktile<3,true,0>(kt,   As, Bs, Ag, Bg, wr, wc, quad, lc,
                        aoff0, aoff1, boff0, cA0, cA1, cB0, acc);
    qkv_ktile<3,true,1>(kt+1, As, Bs, Ag, Bg, wr, wc, quad, lc,
                        aoff0, aoff1, boff0, cA0, cA1, cB0, acc);
    qkv_ktile<3,true,2>(kt+2, As, Bs, Ag, Bg, wr, wc, quad, lc,
                        aoff0, aoff1, boff0, cA0, cA1, cB0, acc);
  }
  qkv_ktile<3,true ,0>(21, As, Bs, Ag, Bg, wr, wc, quad, lc,
                       aoff0, aoff1, boff0, cA0, cA1, cB0, acc);   // stages T23
  qkv_ktile<3,false,1>(22, As, Bs, Ag, Bg, wr, wc, quad, lc,
                       aoff0, aoff1, boff0, cA0, cA1, cB0, acc);
  qkv_ktile<0,false,2>(23, As, Bs, Ag, Bg, wr, wc, quad, lc,
                       aoff0, aoff1, boff0, cA0, cA1, cB0, acc);

  // epilogue (C/D: col=nt*16+lc, row=quad*4+r); per-wave 64-col group = 1 head
  const int cg = n0 + wc*64;
  const int t = cg / HC;                // 0=q, 1=k, 2=v (block-uniform: n0 % 128 == 0)
  const int h = (cg % HC) / HD;
  if (t < 2) {
    short* outp = (t == 0) ? Qb : Kb;
    const float sc = (t == 0) ? 0.125f : 1.0f;   // SCALE = 64^-0.5 for q
#pragma unroll
    for (int i = 0; i < 4; ++i)
#pragma unroll
      for (int r = 0; r < 4; ++r) {
        float s1 = (acc[i][0][r] + acc[i][1][r]) + (acc[i][2][r] + acc[i][3][r]);
        float s2 = acc[i][0][r]*acc[i][0][r];
        s2 = __builtin_fmaf(acc[i][1][r], acc[i][1][r], s2);
        s2 = __builtin_fmaf(acc[i][2][r], acc[i][2][r], s2);
        s2 = __builtin_fmaf(acc[i][3][r], acc[i][3][r], s2);
#pragma unroll
        for (int off = 1; off < 16; off <<= 1) {
          s1 += __shfl_xor(s1, off);
          s2 += __shfl_xor(s2, off);
        }
        const float mean = s1 * (1.0f/64.0f);
        const float var  = s2 * (1.0f/64.0f) - mean*mean;
        const float inv  = rsqrtf(var + 1e-5f) * sc;
        const int row = m0 + wr*64 + i*16 + quad*4 + r;
        const int b = row >> 10, n_in = row & 1023;
        short* rowp = outp + ((size_t)(b*HH + h)*HN + n_in)*HD;
#pragma unroll
        for (int nt = 0; nt < 4; ++nt)
          rowp[nt*16 + lc] = f2bf((acc[i][nt][r] - mean) * inv);
      }
  } else {
    // fused V-transpose: acc -> LDS (key-permuted, stride 268) -> Vtb.
    // Storage col c holds key k: c(k) = ((k&15)<<2)|(k>>4); inverse of
    // attn's perm(c) = (c&3)*16 + (c>>2)  [perm(c(k)) == k].
    short* vs = SMEM;                 // [2][64][268] = 34304 shorts <= 36864
    __syncthreads();                  // main-loop LDS fully consumed by all waves
    const int hd = wc;                // wave's head slot (0/1)
#pragma unroll
    for (int i = 0; i < 4; ++i)
#pragma unroll
      for (int nt = 0; nt < 4; ++nt)
#pragma unroll
        for (int r = 0; r < 4; ++r) {
          const int dd = nt*16 + lc;
          const int k  = i*16 + quad*4 + r;            // row within 64-group
          const int c  = ((k & 15) << 2) | (k >> 4);   // permuted col
          vs[(hd*64 + dd)*268 + wr*64 + c] = f2bf(acc[i][nt][r]);
        }
    __syncthreads();
    const int b = m0 >> 10, m0g = m0 & 1023;
#pragma unroll
    for (int it = 0; it < 8; ++it) {
      const int idx = it*512 + tid;        // [0,4096)
      const int h2 = idx >> 11;            // head slot 0/1
      const int rem = idx & 2047;
      const int dd = rem >> 5, c8 = rem & 31;
      const int habs = ((n0 + h2*64) - 1536) >> 6;     // absolute head
      const short* src = vs + (h2*64 + dd)*268 + c8*8; // 8B-aligned
      s16x4 lo = *(const s16x4*)(src);
      s16x4 hi = *(const s16x4*)(src + 4);
      bf16x8 vvv;
      vvv[0]=lo[0]; vvv[1]=lo[1]; vvv[2]=lo[2]; vvv[3]=lo[3];
      vvv[4]=hi[0]; vvv[5]=hi[1]; vvv[6]=hi[2]; vvv[7]=hi[3];
      *(bf16x8*)(Vtb + ((size_t)((b*HH + habs)*HD + dd))*HN + m0g + c8*8) = vvv;
    }
  }
}

// ---------------- GEMM 2: out = AO * Wproj^T (f32 out) ----------------------
// R14: R11 counted-vmcnt pipeline. BM=128 BN=128 BK=32, 256 thr (4 waves),
// 3 LDS slots = 48 KiB -> 3 blocks/CU; grid 384 co-resident, no tail.
template<int VM, bool STG, int SLOT>
__device__ __forceinline__ void bt_ktile(
    int kt, short* sA, short* sB,
    const short* Ag, const short* Bg,
    int wr, int wc, int quad, int lc,
    int aoff0, int aoff1, int boff0, int boff1,
    int cA0, int cA1, int cB0, int cB1,
    f32x4 (&acc)[4][4])
{
  if constexpr (VM == 4) asm volatile("s_waitcnt vmcnt(4)" ::: "memory");
  else                   asm volatile("s_waitcnt vmcnt(0)" ::: "memory");
  __builtin_amdgcn_s_barrier();
  if constexpr (STG) {
    constexpr int DST = (SLOT + 2) % 3;
    const int kcol = (kt + 2) * 32;
    short* dA = sA + DST*4096;
    short* dB = sB + DST*4096;
    gll16(Ag + (size_t)(aoff0 + kcol), (void*)(dA + cA0*8));
    gll16(Ag + (size_t)(aoff1 + kcol), (void*)(dA + cA1*8));
    gll16(Bg + (size_t)(boff0 + kcol), (void*)(dB + cB0*8));
    gll16(Bg + (size_t)(boff1 + kcol), (void*)(dB + cB1*8));
  }
  const short* sa = sA + SLOT*4096;
  const short* sb = sB + SLOT*4096;
  bf16x8 af[4], bfr[4];
#pragma unroll
  for (int mt = 0; mt < 4; ++mt) {
    const int rA = wr*64 + mt*16 + lc;
    af[mt] = *(const bf16x8*)(sa + rA*32 + (quad ^ ((rA >> 1) & 3))*8);
  }
#pragma unroll
  for (int nt = 0; nt < 4; ++nt) {
    const int rB = wc*64 + nt*16 + lc;
    bfr[nt] = *(const bf16x8*)(sb + rB*32 + (quad ^ ((rB >> 1) & 3))*8);
  }
  __builtin_amdgcn_s_setprio(1);
#pragma unroll
  for (int mt = 0; mt < 4; ++mt)
#pragma unroll
    for (int nt = 0; nt < 4; ++nt)
      acc[mt][nt] = mfma16(af[mt], bfr[nt], acc[mt][nt]);
  __builtin_amdgcn_s_setprio(0);
}

__global__ __launch_bounds__(256, 3) void gemm_bt_f32(const short* __restrict__ A,
                                                      const short* __restrict__ Bw,
                                                      float* __restrict__ C) {
  __shared__ short As[3*128*32];   // 24 KiB
  __shared__ short Bs[3*128*32];   // 24 KiB
  // XCD swizzle: 384 wgs = 8 XCDs x 48 (8 m-panels x 6 n) each.
  const int wg = blockIdx.x;
  const int swz = (wg & 7)*48 + (wg >> 3);
  const int by = swz / 6, bx = swz % 6;
  const int m0 = by*128, n0 = bx*128;
  const int tid = threadIdx.x;
  const int lane = tid & 63, w = tid >> 6, quad = lane >> 4, lc = lane & 15;
  const int wr = w >> 1, wc = w & 1;           // 2 x 2 wave grid
  const int cA0 = tid,        rA0 = cA0 >> 2, sbA0 = ((cA0 & 3) ^ ((rA0 >> 1) & 3))*8;
  const int cA1 = 256 + tid,  rA1 = cA1 >> 2, sbA1 = ((cA1 & 3) ^ ((rA1 >> 1) & 3))*8;
  const int aoff0 = rA0*HC + sbA0;
  const int aoff1 = rA1*HC + sbA1;
  const int cB0 = cA0, cB1 = cA1;
  const int boff0 = aoff0, boff1 = aoff1;      // same mapping, B base differs
  const short* Ag = A  + (size_t)m0*HC;
  const short* Bg = Bw + (size_t)n0*HC;
  f32x4 acc[4][4] = {};

#pragma unroll
  for (int pk = 0; pk < 2; ++pk) {
    gll16(Ag + (size_t)(aoff0 + pk*32), (void*)(As + pk*4096 + cA0*8));
    gll16(Ag + (size_t)(aoff1 + pk*32), (void*)(As + pk*4096 + cA1*8));
    gll16(Bg + (size_t)(boff0 + pk*32), (void*)(Bs + pk*4096 + cB0*8));
    gll16(Bg + (size_t)(boff1 + pk*32), (void*)(Bs + pk*4096 + cB1*8));
  }

#pragma unroll 1
  for (int kt = 0; kt < 21; kt += 3) {
    bt_ktile<4,true,0>(kt,   As, Bs, Ag, Bg, wr, wc, quad, lc,
                       aoff0, aoff1, boff0, boff1, cA0, cA1, cB0, cB1, acc);
    bt_ktile<4,true,1>(kt+1, As, Bs, Ag, Bg, wr, wc, quad, lc,
                       aoff0, aoff1, boff0, boff1, cA0, cA1, cB0, cB1, acc);
    bt_ktile<4,true,2>(kt+2, As, Bs, Ag, Bg, wr, wc, quad, lc,
                       aoff0, aoff1, boff0, boff1, cA0, cA1, cB0, cB1, acc);
  }
  bt_ktile<4,true ,0>(21, As, Bs, Ag, Bg, wr, wc, quad, lc,
                      aoff0, aoff1, boff0, boff1, cA0, cA1, cB0, cB1, acc);  // stages T23
  bt_ktile<4,false,1>(22, As, Bs, Ag, Bg, wr, wc, quad, lc,
                      aoff0, aoff1, boff0, boff1, cA0, cA1, cB0, cB1, acc);
  bt_ktile<0,false,2>(23, As, Bs, Ag, Bg, wr, wc, quad, lc,
                      aoff0, aoff1, boff0, boff1, cA0, cA1, cB0, cB1, acc);

#pragma unroll
  for (int mt = 0; mt < 4; ++mt)
#pragma unroll
    for (int nt = 0; nt < 4; ++nt)
#pragma unroll
      for (int r = 0; r < 4; ++r) {
        const int row = m0 + wr*64 + mt*16 + quad*4 + r;
        const int col = n0 + wc*64 + nt*16 + lc;
        C[(size_t)row*HC + col] = acc[mt][nt][r];
      }
}

// ---------------- flash attention: 128 q-rows/block, 64-key chunks ----------
// R9 structure; R13: XCD-grouped block swizzle (all 8 q-tiles of each bh on
// one XCD -> per-XCD K/V working set 12*256KB = 3MB fits the 4MB L2).
__global__ __launch_bounds__(256, 3) void attn_kernel(const short* __restrict__ Qb,
                                                      const short* __restrict__ Kb,
                                                      const short* __restrict__ Vtb,
                                                      short* __restrict__ AOb) {
  const int raw = blockIdx.x;
  const int blk = (raw & 7)*96 + (raw >> 3);   // bijective on [0,768)
  const int qt = blk & 7, bh = blk >> 3;
  const int b = bh / HH, h = bh % HH;
  const int tid = threadIdx.x, w = tid >> 6, lane = tid & 63;
  const int quad = lane >> 4, lc = lane & 15;

  __shared__ short Ks [64][72];      // K chunk: row=key(natural), padded
  __shared__ short Vts[64][72];      // V chunk: row=d, cols=64 keys permuted
  __shared__ short Ps [4][32][72];   // per-wave P stash (32 q-rows), permuted keys

  // Q A-fragments: A[m=lane&15][k=quad*8+j]; wave rows qt*128 + w*32 + mt*16
  bf16x8 aq[2][2];
#pragma unroll
  for (int mt = 0; mt < 2; ++mt) {
    const int mrow = qt*128 + w*32 + mt*16 + lc;
    aq[mt][0] = *(const bf16x8*)(Qb + ((size_t)bh*HN + mrow)*HD + quad*8);
    aq[mt][1] = *(const bf16x8*)(Qb + ((size_t)bh*HN + mrow)*HD + 32 + quad*8);
  }

  const short* kbh = Kb  + (size_t)bh*HN*HD;
  const short* vbh = Vtb + (size_t)bh*HD*HN;

  f32x4 oacc[2][4] = {};
  float l_i[2][4] = {};

  // staging regs: c = i*256+tid in [0,512); row=c>>3 in [0,64), cb=c&7
  bf16x8 gk[2], gv[2];
#pragma unroll
  for (int i = 0; i < 2; ++i) {
    const int c = i*256 + tid;
    gk[i] = *(const bf16x8*)(kbh + (size_t)(c >> 3)*HD + (c & 7)*8);
    gv[i] = *(const bf16x8*)(vbh + (size_t)(c >> 3)*HN + (c & 7)*8);
  }
#pragma unroll
  for (int i = 0; i < 2; ++i) {
    const int c = i*256 + tid;
    *(bf16x8*)(&Ks [c >> 3][(c & 7)*8]) = gk[i];
    *(bf16x8*)(&Vts[c >> 3][(c & 7)*8]) = gv[i];
  }
  __syncthreads();

  const float LOG2E = 1.44269504f;
  const float MB2   = 8.0f * 1.44269504f;   // fixed max * log2(e)

  for (int ck = 0; ck < 16; ++ck) {
    // prefetch chunk ck+1 into registers (overlaps with compute below)
    if (ck < 15) {
      const int nn0 = (ck + 1)*64;
#pragma unroll
      for (int i = 0; i < 2; ++i) {
        const int c = i*256 + tid;
        gk[i] = *(const bf16x8*)(kbh + (size_t)(nn0 + (c >> 3))*HD + (c & 7)*8);
        gv[i] = *(const bf16x8*)(vbh + (size_t)(c >> 3)*HN + nn0 + (c & 7)*8);
      }
    }

    // S = Q K^T : 16 MFMAs (2 m-tiles x 2 kk x 4 nt)
    f32x4 sacc[2][4] = {};
#pragma unroll
    for (int kk = 0; kk < 2; ++kk)
#pragma unroll
      for (int nt = 0; nt < 4; ++nt) {
        bf16x8 bk = *(const bf16x8*)(&Ks[nt*16 + lc][kk*32 + quad*8]);
#pragma unroll
        for (int mt = 0; mt < 2; ++mt)
          sacc[mt][nt] = mfma16(aq[mt][kk], bk, sacc[mt][nt]);
      }

    // fixed-max softmax + P stash (C->A relayout, ds_write_b64 per row)
#pragma unroll
    for (int mt = 0; mt < 2; ++mt)
#pragma unroll
      for (int r = 0; r < 4; ++r) {
        float ps[4];
#pragma unroll
        for (int nt = 0; nt < 4; ++nt) {
          ps[nt] = fast_exp2(__builtin_fmaf(sacc[mt][nt][r], LOG2E, -MB2));
          sacc[mt][nt][r] = ps[nt];
        }
        l_i[mt][r] += (ps[0] + ps[1]) + (ps[2] + ps[3]);
        uint2 pk;
        pk.x = pack_bf16_rne(ps[0], ps[1]);
        pk.y = pack_bf16_rne(ps[2], ps[3]);
        *(uint2*)(&Ps[w][mt*16 + quad*4 + r][lc*4]) = pk;
      }

    // O += P V : 16 MFMAs (A from Ps, B from Vts; both in permuted key space)
#pragma unroll
    for (int kk = 0; kk < 2; ++kk) {
      bf16x8 ap[2];
#pragma unroll
      for (int mt = 0; mt < 2; ++mt)
        ap[mt] = *(const bf16x8*)(&Ps[w][mt*16 + lc][kk*32 + quad*8]);
#pragma unroll
      for (int nt2 = 0; nt2 < 4; ++nt2) {
        bf16x8 bv = *(const bf16x8*)(&Vts[nt2*16 + lc][kk*32 + quad*8]);
#pragma unroll
        for (int mt = 0; mt < 2; ++mt)
          oacc[mt][nt2] = mfma16(ap[mt], bv, oacc[mt][nt2]);
      }
    }

    if (ck < 15) {
      __syncthreads();   // all waves done reading Ks/Vts
#pragma unroll
      for (int i = 0; i < 2; ++i) {
        const int c = i*256 + tid;
        *(bf16x8*)(&Ks [c >> 3][(c & 7)*8]) = gk[i];
        *(bf16x8*)(&Vts[c >> 3][(c & 7)*8]) = gv[i];
      }
      __syncthreads();
    }
  }

  // epilogue: reduce l across the 16 lanes of each quad, then scale & store
#pragma unroll
  for (int mt = 0; mt < 2; ++mt)
#pragma unroll
    for (int r = 0; r < 4; ++r) {
      float l = l_i[mt][r];
#pragma unroll
      for (int off = 1; off < 16; off <<= 1) l += __shfl_xor(l, off);
      const float rl = 1.0f / l;
      const int row = qt*128 + w*32 + mt*16 + quad*4 + r;
#pragma unroll
      for (int nt2 = 0; nt2 < 4; ++nt2) {
        const int d = nt2*16 + lc;
        AOb[((size_t)(b*HN + row))*HC + h*HD + d] = f2bf(oacc[mt][nt2][r] * rl);
      }
    }
}

// ---------------- launch ----------------
extern "C" void kernel_launch(void* const* d_in, const int* in_sizes, int n_in,
                              void* d_out, int out_size, void* d_ws, size_t ws_size,
                              hipStream_t stream) {
  const float* x     = (const float*)d_in[0];
  const float* wqkv  = (const float*)d_in[1];
  const float* wproj = (const float*)d_in[2];
  float* out = (float*)d_out;

  char* ws = (char*)d_ws;
  size_t off = 0;
  auto alloc = [&](size_t bytes) -> void* {
    void* p = ws + off; off += (bytes + 255) & ~(size_t)255; return p;
  };
  short* xb     = (short*)alloc((size_t)ROWS*HC*2);        // 12.6 MB
  short* wqkvb  = (short*)alloc((size_t)3*HC*HC*2);        //  3.5 MB
  short* wprojb = (short*)alloc((size_t)HC*HC*2);          //  1.2 MB
  short* Qb     = (short*)alloc((size_t)BH*HN*HD*2);       // 12.6 MB
  short* Kb     = (short*)alloc((size_t)BH*HN*HD*2);       // 12.6 MB
  short* Vtb    = (short*)alloc((size_t)BH*HD*HN*2);       // 12.6 MB
  short* AOb    = (short*)alloc((size_t)ROWS*HC*2);        // 12.6 MB  (~68 MB total)

  { const int n0 = ROWS*HC/4, n1 = 3*HC*HC/4, n2 = HC*HC/4;
    const int tot = n0 + n1 + n2;
    cvt3_kernel<<<(tot + 255)/256, 256, 0, stream>>>(x, xb, n0, wqkv, wqkvb, n1,
                                                     wproj, wprojb, n2); }

  // 576 = 32 m-blocks x 18 n-blocks, XCD-swizzled inside the kernel
  gemm_qkv<<<dim3(576), 512, 0, stream>>>(xb, wqkvb, Qb, Kb, Vtb);
  attn_kernel<<<BH*8, 256, 0, stream>>>(Qb, Kb, Vtb, AOb);
  // 384 = 64 m-blocks x 6 n-blocks, XCD-swizzled inside the kernel
  gemm_bt_f32<<<dim3(384), 256, 0, stream>>>(AOb, wprojb, out);
}